// Round 3
// baseline (336.859 us; speedup 1.0000x reference)
//
#include <hip/hip_runtime.h>
#include <hip/hip_bf16.h>

#define A_N 16
#define B_N 8192
#define O_N 128
#define ACT_N 16
#define H_N 128
#define NH_N 4
#define D_N 32
#define IN_N 144
#define NEGV -1e9f

typedef __attribute__((ext_vector_type(8))) short short8;
typedef __attribute__((ext_vector_type(4))) float floatx4;

// ---- bf16 helpers (RNE) -------------------------------------------------
static __device__ inline unsigned short f2bf(float f) {
    union { float f; unsigned u; } x{f};
    unsigned u = x.u + 0x7FFFu + ((x.u >> 16) & 1u);
    return (unsigned short)(u >> 16);
}
static __device__ inline unsigned pack_bf2(float a, float b) {
    union { float f; unsigned u; } xa{a}, xb{b};
    unsigned ua = xa.u + 0x7FFFu + ((xa.u >> 16) & 1u);
    unsigned ub = xb.u + 0x7FFFu + ((xb.u >> 16) & 1u);
    return (ua >> 16) | (ub & 0xFFFF0000u);
}
static __device__ inline float bf2f(unsigned short h) {
    union { unsigned u; float f; } x;
    x.u = ((unsigned)h) << 16;
    return x.f;
}
static __device__ inline float bflo(unsigned u) {
    union { unsigned u; float f; } x; x.u = u << 16; return x.f;
}
static __device__ inline float bfhi(unsigned u) {
    union { unsigned u; float f; } x; x.u = u & 0xFFFF0000u; return x.f;
}
static __device__ inline short8 ld_frag(const unsigned* p) {
    union { unsigned u[4]; short8 v; } x;
    uint2 lo = *(const uint2*)p;
    uint2 hi = *(const uint2*)(p + 2);
    x.u[0] = lo.x; x.u[1] = lo.y; x.u[2] = hi.x; x.u[3] = hi.y;
    return x.v;
}
static __device__ inline short8 ld_frag4(const unsigned* p) {
    union { uint4 q; short8 v; } x;
    x.q = *(const uint4*)p;
    return x.v;
}

// ---- misc small kernels -------------------------------------------------
__global__ __launch_bounds__(256) void k_zero(float* p, int n) {
    int i = blockIdx.x * 256 + threadIdx.x;
    if (i < n) p[i] = 0.f;
}

__global__ __launch_bounds__(256) void k_stats(const float* __restrict__ obs,
                                               const float* __restrict__ act,
                                               float* __restrict__ gsum,
                                               float* __restrict__ gsq) {
    __shared__ float ssum[IN_N];
    __shared__ float ssq[IN_N];
    int a = blockIdx.x >> 5;
    int r0 = (blockIdx.x & 31) * 256;
    int t = threadIdx.x;
    if (t < IN_N) { ssum[t] = 0.f; ssq[t] = 0.f; }
    __syncthreads();
    if (t < 128) {
        const float* p = obs + ((size_t)a * B_N + r0) * O_N + t;
        float s = 0.f, q = 0.f;
#pragma unroll 4
        for (int r = 0; r < 256; ++r) {
            float v = p[(size_t)r * O_N];
            s += v; q += v * v;
        }
        ssum[t] = s; ssq[t] = q;
    } else {
        int tt = t - 128;
        int f = tt & 15, rg = tt >> 4;
        const float* p = act + ((size_t)a * B_N + r0 + rg) * ACT_N + f;
        float s = 0.f, q = 0.f;
#pragma unroll 4
        for (int i = 0; i < 32; ++i) {
            float v = p[(size_t)i * 8 * ACT_N];
            s += v; q += v * v;
        }
        atomicAdd(&ssum[O_N + f], s);
        atomicAdd(&ssq[O_N + f], q);
    }
    __syncthreads();
    if (t < IN_N) {
        atomicAdd(&gsum[a * IN_N + t], ssum[t]);
        atomicAdd(&gsq[a * IN_N + t], ssq[t]);
    }
}

__global__ __launch_bounds__(256) void k_finalize(float* gsum, float* gsq) {
    int i = blockIdx.x * 256 + threadIdx.x;
    if (i < A_N * IN_N) {
        const float invB = 1.f / (float)B_N;
        float m = gsum[i] * invB;
        float v = fmaxf(gsq[i] * invB - m * m, 0.f);
        gsum[i] = m;
        gsq[i] = rsqrtf(v + 1e-5f);
    }
}

// ---- weight prep: fp32 -> bf16, transposed to [n][k/2] packed uints -----
// wt_l1 rows pre-scaled by rstd (BN folded into weights).
// wt_c2: Wc2 transposed to [a][o][h] fp32 for contiguous critic-tail reads.
#define L1E 393216
#define P1E 409600
#define P2E 417792
#define CRE 679936
#define C2E 712704
__global__ __launch_bounds__(256) void k_wprep(
    const float* __restrict__ W_sa, const float* __restrict__ W_s,
    const float* __restrict__ Wk, const float* __restrict__ Wsel,
    const float* __restrict__ Wv, const float* __restrict__ Wc1,
    const float* __restrict__ Wc2, const float* __restrict__ rstd,
    unsigned* __restrict__ wt_l1, unsigned* __restrict__ wt_p1,
    unsigned* __restrict__ wt_p2, unsigned* __restrict__ wt_cr,
    float* __restrict__ wt_c2) {
    int idx = blockIdx.x * 256 + threadIdx.x;
    if (idx < L1E) {
        int a = idx / 24576, rem = idx % 24576;
        int n = rem & 255, kp = rem >> 8;  // kp 0..95
        int k0 = 2 * kp, k1 = k0 + 1;
        float v0 = 0.f, v1 = 0.f;
        if (n < 128) {
            if (k0 < IN_N) v0 = W_sa[((size_t)a * IN_N + k0) * H_N + n] * rstd[a * IN_N + k0];
            if (k1 < IN_N) v1 = W_sa[((size_t)a * IN_N + k1) * H_N + n] * rstd[a * IN_N + k1];
        } else {
            int m = n - 128;
            if (k0 < O_N) v0 = W_s[((size_t)a * O_N + k0) * H_N + m] * rstd[a * IN_N + k0];
            if (k1 < O_N) v1 = W_s[((size_t)a * O_N + k1) * H_N + m] * rstd[a * IN_N + k1];
        }
        wt_l1[(size_t)a * 24576 + n * 96 + kp] = pack_bf2(v0, v1);
    } else if (idx < P1E) {
        int i2 = idx - L1E;
        int n = i2 & 255, kp = i2 >> 8;
        int k0 = 2 * kp;
        float v0, v1;
        if (n < 128) {
            const float* w = Wk + ((size_t)(n >> 5) * H_N) * D_N + (n & 31);
            v0 = w[(size_t)k0 * D_N]; v1 = w[(size_t)(k0 + 1) * D_N];
        } else {
            int m = n - 128;
            const float* w = Wv + ((size_t)(m >> 5) * H_N) * D_N + (m & 31);
            v0 = w[(size_t)k0 * D_N]; v1 = w[(size_t)(k0 + 1) * D_N];
        }
        wt_p1[n * 64 + kp] = pack_bf2(v0, v1);
    } else if (idx < P2E) {
        int i3 = idx - P1E;
        int n = i3 & 127, kp = i3 >> 7;
        int k0 = 2 * kp;
        const float* w = Wsel + ((size_t)(n >> 5) * H_N) * D_N + (n & 31);
        wt_p2[n * 64 + kp] = pack_bf2(w[(size_t)k0 * D_N], w[(size_t)(k0 + 1) * D_N]);
    } else if (idx < CRE) {
        int i4 = idx - P2E;
        int a = i4 >> 14, r = i4 & 16383;
        int n = r & 127, kp = r >> 7;
        int k0 = 2 * kp;
        const float* w = Wc1 + (size_t)a * 256 * H_N + n;
        wt_cr[(size_t)a * 16384 + n * 128 + kp] =
            pack_bf2(w[(size_t)k0 * H_N], w[(size_t)(k0 + 1) * H_N]);
    } else if (idx < C2E) {
        int i5 = idx - CRE;
        int a = i5 >> 11, rem = i5 & 2047;
        int oo = rem >> 7, h = rem & 127;
        wt_c2[i5] = Wc2[((size_t)a * H_N + h) * ACT_N + oo];
    }
}

// ---- folded biases: fb[0][a][c] = b_sa - sum(m*r*W_sa); fb[1] for se ----
__global__ __launch_bounds__(256) void k_bfold(
    const float* __restrict__ mean, const float* __restrict__ rstd,
    const float* __restrict__ W_sa, const float* __restrict__ W_s,
    const float* __restrict__ b_sa, const float* __restrict__ b_s,
    float* __restrict__ fb) {
    int a = blockIdx.x, c = threadIdx.x;
    float s = 0.f;
    if (c < 128) {
        for (int k = 0; k < IN_N; ++k)
            s += mean[a * IN_N + k] * rstd[a * IN_N + k] *
                 W_sa[((size_t)a * IN_N + k) * H_N + c];
        fb[a * 128 + c] = b_sa[a * H_N + c] - s;
    } else {
        int m = c - 128;
        for (int k = 0; k < O_N; ++k)
            s += mean[a * IN_N + k] * rstd[a * IN_N + k] *
                 W_s[((size_t)a * O_N + k) * H_N + m];
        fb[2048 + a * 128 + m] = b_s[a * H_N + m] - s;
    }
}

// ---- L1 merged: one block does BOTH sa (cols 0-127) and se (128-255). ---
// X tile K=160 (obs 128 | act 16 | pad 16); se weight rows are zero for
// k>=128 so the act columns contribute 0 to se. obs read ONCE.
// Output layout batch-major: row index (b_local*16 + a).
__global__ __launch_bounds__(512, 2) void k_l1(
    const float* __restrict__ obs, const float* __restrict__ act,
    const unsigned* __restrict__ wt_l1, const float* __restrict__ fb,
    unsigned short* __restrict__ sa_us, unsigned short* __restrict__ se_us,
    int b0g, int Bc) {
    __shared__ unsigned smem[(128 + 256) * 34];
    unsigned* Xs = smem;
    unsigned* Ws = smem + 128 * 34;

    int a = blockIdx.y;
    int b0 = blockIdx.x * 128;
    int t = threadIdx.x;
    int wid = t >> 6, lane = t & 63, lm = lane & 15, lq = lane >> 4;
    int wrow = (wid & 1) * 64;
    int wcol = (wid >> 1) * 64;  // 0,64 -> sa; 128,192 -> se

    floatx4 acc[4][4];
#pragma unroll
    for (int mt = 0; mt < 4; ++mt)
#pragma unroll
        for (int nt = 0; nt < 4; ++nt)
#pragma unroll
            for (int e = 0; e < 4; ++e) acc[mt][nt][e] = 0.f;

    const unsigned* WtA = wt_l1 + (size_t)a * 24576;

    for (int c = 0; c < 3; ++c) {
        int kk = c * 64;
        __syncthreads();
        // X: 128 rows x 16 float4 per chunk (4 iters/thread @512)
        for (int idx = t; idx < 128 * 16; idx += 512) {
            int r = idx >> 4, c4 = idx & 15;
            int k = kk + c4 * 4;
            size_t grow = (size_t)a * B_N + b0g + b0 + r;
            float4 v;
            if (k < O_N) v = *(const float4*)&obs[grow * O_N + k];
            else if (k < IN_N) v = *(const float4*)&act[grow * ACT_N + (k - O_N)];
            else v = make_float4(0.f, 0.f, 0.f, 0.f);
            uint2* dst = (uint2*)&Xs[r * 34 + c4 * 2];
            *dst = make_uint2(pack_bf2(v.x, v.y), pack_bf2(v.z, v.w));
        }
        // W: 256 n-rows x 8 uint4 per chunk (4 iters/thread @512)
        for (int idx = t; idx < 256 * 8; idx += 512) {
            int n = idx >> 3, c4 = idx & 7;
            uint4 w = *(const uint4*)&WtA[(size_t)n * 96 + (kk >> 1) + c4 * 4];
            uint2* dst = (uint2*)&Ws[n * 34 + c4 * 4];
            dst[0] = make_uint2(w.x, w.y);
            dst[1] = make_uint2(w.z, w.w);
        }
        __syncthreads();
#pragma unroll
        for (int s = 0; s < 2; ++s) {
            if (kk + s * 32 >= 160) break;
            short8 afr[4];
#pragma unroll
            for (int mt = 0; mt < 4; ++mt)
                afr[mt] = ld_frag(&Xs[(wrow + mt * 16 + lm) * 34 + s * 16 + lq * 4]);
#pragma unroll
            for (int nt = 0; nt < 4; ++nt) {
                short8 bfr = ld_frag(&Ws[(wcol + nt * 16 + lm) * 34 + s * 16 + lq * 4]);
#pragma unroll
                for (int mt = 0; mt < 4; ++mt)
                    acc[mt][nt] = __builtin_amdgcn_mfma_f32_16x16x32_bf16(
                        afr[mt], bfr, acc[mt][nt], 0, 0, 0);
            }
        }
    }

    int zsel = (wcol >= 128);
    unsigned short* outp = zsel ? se_us : sa_us;
    const float* bias = fb + zsel * 2048 + a * 128;
    int cbase = wcol & 127;
#pragma unroll
    for (int mt = 0; mt < 4; ++mt)
#pragma unroll
        for (int nt = 0; nt < 4; ++nt)
#pragma unroll
            for (int r = 0; r < 4; ++r) {
                int row = wrow + mt * 16 + lq * 4 + r;
                int col = cbase + nt * 16 + lm;
                float v = acc[mt][nt][r] + bias[col];
                v = v > 0.f ? v : 0.01f * v;
                outp[((size_t)(b0 + row) * 16 + a) * 128 + col] = f2bf(v);
            }
}

// ---- fused: PRIVATIZED — one wave owns one batch element, NO barriers. --
// Per wave: M=16 GEMMs (keys/vals/sel) from in-reg A-frags + L2-resident
// B-frags; wave-private LDS transpose buffers; QK^T MFMA; scalar softmax/PV.
// Waves free-run across phases -> cross-wave pipe overlap without barriers.
__global__ __launch_bounds__(256, 3) void k_fused(
    const unsigned* __restrict__ sa_u, const unsigned* __restrict__ se_u,
    const unsigned* __restrict__ wt_p1, const unsigned* __restrict__ wt_p2,
    const float* __restrict__ bv, unsigned short* __restrict__ other_us,
    int Bc) {
    // per-wave slices: [wave][3 bufs][16 rows][136 shorts] = 12.75 KB/wave
    __shared__ unsigned short lds[4][3][16][136];

    int t = threadIdx.x;
    int wid = t >> 6, lane = t & 63, lm = lane & 15, lq = lane >> 4;
    int b = blockIdx.x * 4 + wid;

    unsigned short* keysS = &lds[wid][0][0][0];
    unsigned short* valsS = &lds[wid][1][0][0];
    unsigned short* selS  = &lds[wid][2][0][0];

    const unsigned* sap = sa_u + (size_t)b * 1024;  // 16 agents x 64 uints
    const unsigned* sep = se_u + (size_t)b * 1024;

    // A-fragments: row = agent = lm, k-slice s (k = s*32 + lq*8 .. +8)
    short8 saf[4], sef[4];
#pragma unroll
    for (int s = 0; s < 4; ++s) saf[s] = ld_frag4(sap + lm * 64 + s * 16 + lq * 4);
#pragma unroll
    for (int s = 0; s < 4; ++s) sef[s] = ld_frag4(sep + lm * 64 + s * 16 + lq * 4);

    // ---- keys GEMM: 16x128, K=128 ----
#pragma unroll
    for (int ct = 0; ct < 8; ++ct) {
        floatx4 acc = {0.f, 0.f, 0.f, 0.f};
        const unsigned* wb = wt_p1 + (size_t)(ct * 16 + lm) * 64 + lq * 4;
#pragma unroll
        for (int s = 0; s < 4; ++s)
            acc = __builtin_amdgcn_mfma_f32_16x16x32_bf16(saf[s], ld_frag4(wb + s * 16),
                                                          acc, 0, 0, 0);
        int col = ct * 16 + lm;
#pragma unroll
        for (int r = 0; r < 4; ++r)
            keysS[(lq * 4 + r) * 136 + col] = f2bf(acc[r]);
    }
    // ---- vals GEMM (+bias, lrelu) ----
#pragma unroll
    for (int ct = 0; ct < 8; ++ct) {
        floatx4 acc = {0.f, 0.f, 0.f, 0.f};
        const unsigned* wb = wt_p1 + (size_t)(128 + ct * 16 + lm) * 64 + lq * 4;
#pragma unroll
        for (int s = 0; s < 4; ++s)
            acc = __builtin_amdgcn_mfma_f32_16x16x32_bf16(saf[s], ld_frag4(wb + s * 16),
                                                          acc, 0, 0, 0);
        int col = ct * 16 + lm;
        float bvc = bv[col];
#pragma unroll
        for (int r = 0; r < 4; ++r) {
            float v = acc[r] + bvc;
            v = v > 0.f ? v : 0.01f * v;
            valsS[(lq * 4 + r) * 136 + col] = f2bf(v);
        }
    }
    // ---- sel GEMM ----
#pragma unroll
    for (int ct = 0; ct < 8; ++ct) {
        floatx4 acc = {0.f, 0.f, 0.f, 0.f};
        const unsigned* wb = wt_p2 + (size_t)(ct * 16 + lm) * 64 + lq * 4;
#pragma unroll
        for (int s = 0; s < 4; ++s)
            acc = __builtin_amdgcn_mfma_f32_16x16x32_bf16(sef[s], ld_frag4(wb + s * 16),
                                                          acc, 0, 0, 0);
        int col = ct * 16 + lm;
#pragma unroll
        for (int r = 0; r < 4; ++r)
            selS[(lq * 4 + r) * 136 + col] = f2bf(acc[r]);
    }

    asm volatile("" ::: "memory");  // order LDS short-writes before uint reads

    // ---- QK^T: one mfma per head; A=sel rows, B=keys rows ----
    const unsigned* selU = (const unsigned*)selS;
    const unsigned* keysU = (const unsigned*)keysS;
    floatx4 lgacc[4];
#pragma unroll
    for (int n = 0; n < 4; ++n) {
        short8 af = ld_frag(selU + lm * 68 + n * 16 + lq * 4);
        short8 bf = ld_frag(keysU + lm * 68 + n * 16 + lq * 4);
        floatx4 z4 = {0.f, 0.f, 0.f, 0.f};
        lgacc[n] = __builtin_amdgcn_mfma_f32_16x16x32_bf16(af, bf, z4, 0, 0, 0);
    }

    asm volatile("" ::: "memory");  // all QK reads issued before lg overwrite

    // lg (f32) overwrites sel slice: [n][i][j], 4 KB
    float* lgs = (float*)selS;
#pragma unroll
    for (int n = 0; n < 4; ++n)
#pragma unroll
        for (int r = 0; r < 4; ++r)
            lgs[(n * 16 + lq * 4 + r) * 16 + lm] =
                lgacc[n][r] * 0.17677669529663687f;

    asm volatile("" ::: "memory");

    // ---- softmax + PV: lane role (head n2 = lq, agent i2 = lm) ----
    int n2 = lq, i2 = lm;
    float lg[16];
    {
        const float4* lgp = (const float4*)&lgs[(n2 * 16 + i2) * 16];
#pragma unroll
        for (int c = 0; c < 4; ++c) {
            float4 v = lgp[c];
            lg[4 * c] = v.x; lg[4 * c + 1] = v.y;
            lg[4 * c + 2] = v.z; lg[4 * c + 3] = v.w;
        }
    }
    lg[i2] = NEGV;
    float m = lg[0];
#pragma unroll
    for (int j = 1; j < 16; ++j) m = fmaxf(m, lg[j]);
    float sum = 0.f;
#pragma unroll
    for (int j = 0; j < 16; ++j) { lg[j] = __expf(lg[j] - m); sum += lg[j]; }
    float inv = 1.f / sum;
#pragma unroll
    for (int j = 0; j < 16; ++j) lg[j] *= inv;

    const unsigned* valsU = (const unsigned*)valsS;
    float ov[32];
#pragma unroll
    for (int u = 0; u < 32; ++u) ov[u] = 0.f;
#pragma unroll
    for (int j = 0; j < 16; ++j) {
        const uint4* vrow = (const uint4*)(valsU + j * 68 + n2 * 16);
        float w = lg[j];
#pragma unroll
        for (int c = 0; c < 4; ++c) {
            uint4 x = vrow[c];
            ov[8 * c + 0] = fmaf(w, bflo(x.x), ov[8 * c + 0]);
            ov[8 * c + 1] = fmaf(w, bfhi(x.x), ov[8 * c + 1]);
            ov[8 * c + 2] = fmaf(w, bflo(x.y), ov[8 * c + 2]);
            ov[8 * c + 3] = fmaf(w, bfhi(x.y), ov[8 * c + 3]);
            ov[8 * c + 4] = fmaf(w, bflo(x.z), ov[8 * c + 4]);
            ov[8 * c + 5] = fmaf(w, bfhi(x.z), ov[8 * c + 5]);
            ov[8 * c + 6] = fmaf(w, bflo(x.w), ov[8 * c + 6]);
            ov[8 * c + 7] = fmaf(w, bfhi(x.w), ov[8 * c + 7]);
        }
    }
    {
        uint4* orow = (uint4*)&other_us[((size_t)b * 16 + i2) * 128 + n2 * 32];
#pragma unroll
        for (int h = 0; h < 2; ++h) {
            uint4 o;
            o.x = pack_bf2(ov[16 * h + 0], ov[16 * h + 1]);
            o.y = pack_bf2(ov[16 * h + 2], ov[16 * h + 3]);
            o.z = pack_bf2(ov[16 * h + 4], ov[16 * h + 5]);
            o.w = pack_bf2(ov[16 * h + 6], ov[16 * h + 7]);
            orow[2 * h] = o;
            o.x = pack_bf2(ov[16 * h + 8], ov[16 * h + 9]);
            o.y = pack_bf2(ov[16 * h + 10], ov[16 * h + 11]);
            o.z = pack_bf2(ov[16 * h + 12], ov[16 * h + 13]);
            o.w = pack_bf2(ov[16 * h + 14], ov[16 * h + 15]);
            orow[2 * h + 1] = o;
        }
    }
}

// ---- critic: block 64 rows x 128 cols, wave 32x64, acc[2][4] ------------
// batch-major inputs: X rows at stride 16*256 B (256 B contiguous chunks).
__global__ __launch_bounds__(256, 4) void k_critic(
    const unsigned* __restrict__ se_u, const unsigned* __restrict__ other_u,
    const unsigned* __restrict__ wt_cr,
    const float* __restrict__ bc1, const float* __restrict__ actions,
    const float* __restrict__ wt_c2, const float* __restrict__ bc2,
    float* __restrict__ qout, int b0g, int Bc) {
    __shared__ unsigned smem[(64 + 128) * 34];
    unsigned* Xs = smem;
    unsigned* Ws = smem + 64 * 34;

    int a = blockIdx.y;
    int b0 = blockIdx.x * 64;
    int t = threadIdx.x;
    int wid = t >> 6, lane = t & 63, lm = lane & 15, lq = lane >> 4;
    int wrow = (wid & 1) * 32;
    int wcol = (wid >> 1) * 64;

    floatx4 acc[2][4];
#pragma unroll
    for (int mt = 0; mt < 2; ++mt)
#pragma unroll
        for (int nt = 0; nt < 4; ++nt)
#pragma unroll
            for (int e = 0; e < 4; ++e) acc[mt][nt][e] = 0.f;

    const unsigned* WtA = wt_cr + (size_t)a * 16384;

    for (int c = 0; c < 4; ++c) {
        int kk = c * 64;
        __syncthreads();
        const unsigned* src = (c < 2) ? se_u : other_u;
        int off = (c & 1) * 32;
        for (int idx = t; idx < 64 * 8; idx += 256) {
            int r = idx >> 3, c4 = idx & 7;
            uint4 v = *(const uint4*)&src[((size_t)(b0 + r) * 16 + a) * 64 + off + c4 * 4];
            uint2* dst = (uint2*)&Xs[r * 34 + c4 * 4];
            dst[0] = make_uint2(v.x, v.y);
            dst[1] = make_uint2(v.z, v.w);
        }
        for (int idx = t; idx < 128 * 8; idx += 256) {
            int n = idx >> 3, c4 = idx & 7;
            uint4 w = *(const uint4*)&WtA[(size_t)n * 128 + (kk >> 1) + c4 * 4];
            uint2* dst = (uint2*)&Ws[n * 34 + c4 * 4];
            dst[0] = make_uint2(w.x, w.y);
            dst[1] = make_uint2(w.z, w.w);
        }
        __syncthreads();
#pragma unroll
        for (int s = 0; s < 2; ++s) {
            short8 afr[2];
#pragma unroll
            for (int mt = 0; mt < 2; ++mt)
                afr[mt] = ld_frag(&Xs[(wrow + mt * 16 + lm) * 34 + s * 16 + lq * 4]);
#pragma unroll
            for (int nt = 0; nt < 4; ++nt) {
                short8 bfr = ld_frag(&Ws[(wcol + nt * 16 + lm) * 34 + s * 16 + lq * 4]);
#pragma unroll
                for (int mt = 0; mt < 2; ++mt)
                    acc[mt][nt] = __builtin_amdgcn_mfma_f32_16x16x32_bf16(
                        afr[mt], bfr, acc[mt][nt], 0, 0, 0);
            }
        }
    }

    __syncthreads();
    unsigned short* hbuf = (unsigned short*)smem;  // [64][132]
#pragma unroll
    for (int mt = 0; mt < 2; ++mt)
#pragma unroll
        for (int nt = 0; nt < 4; ++nt)
#pragma unroll
            for (int r = 0; r < 4; ++r) {
                int row = wrow + mt * 16 + lq * 4 + r;
                int col = wcol + nt * 16 + lm;
                float v = acc[mt][nt][r] + bc1[a * H_N + col];
                v = v > 0.f ? v : 0.01f * v;
                hbuf[row * 132 + col] = f2bf(v);
            }
    __syncthreads();
    if (t < 64) {
        size_t arow = (size_t)a * B_N + b0g + b0 + t;
        const float* ap = &actions[arow * ACT_N];
        float bestv = ap[0];
        int bi = 0;
        for (int o = 1; o < ACT_N; ++o) {
            float v = ap[o];
            if (v > bestv) { bestv = v; bi = o; }
        }
        float q = bc2[a * ACT_N + bi];
        const float4* w4p = (const float4*)&wt_c2[((size_t)a * ACT_N + bi) * H_N];
        const uint2* hp2 = (const uint2*)&hbuf[t * 132];
#pragma unroll
        for (int h4 = 0; h4 < 32; ++h4) {
            float4 w4 = w4p[h4];
            uint2 hh = hp2[h4];
            q = fmaf(bflo(hh.x), w4.x, q);
            q = fmaf(bfhi(hh.x), w4.y, q);
            q = fmaf(bflo(hh.y), w4.z, q);
            q = fmaf(bfhi(hh.y), w4.w, q);
        }
        qout[arow] = q;
    }
}

extern "C" void kernel_launch(void* const* d_in, const int* in_sizes, int n_in,
                              void* d_out, int out_size, void* d_ws, size_t ws_size,
                              hipStream_t stream) {
    const float* obs     = (const float*)d_in[0];
    const float* actions = (const float*)d_in[1];
    const float* W_sa    = (const float*)d_in[2];
    const float* b_sa    = (const float*)d_in[3];
    const float* W_s     = (const float*)d_in[4];
    const float* b_s     = (const float*)d_in[5];
    const float* Wk      = (const float*)d_in[6];
    const float* Wsel    = (const float*)d_in[7];
    const float* Wv      = (const float*)d_in[8];
    const float* bv      = (const float*)d_in[9];
    const float* Wc1     = (const float*)d_in[10];
    const float* bc1     = (const float*)d_in[11];
    const float* Wc2     = (const float*)d_in[12];
    const float* bc2     = (const float*)d_in[13];
    float* out = (float*)d_out;
    char* ws = (char*)d_ws;

    size_t o = 0;
    float* gsum = (float*)(ws + o); o += 2304 * 4;
    float* gsq  = (float*)(ws + o); o += 2304 * 4;
    unsigned* wt_l1 = (unsigned*)(ws + o); o += (size_t)393216 * 4;
    unsigned* wt_p1 = (unsigned*)(ws + o); o += (size_t)16384 * 4;
    unsigned* wt_p2 = (unsigned*)(ws + o); o += (size_t)8192 * 4;
    unsigned* wt_cr = (unsigned*)(ws + o); o += (size_t)262144 * 4;
    float* fb = (float*)(ws + o); o += (size_t)4096 * 4;
    float* wt_c2 = (float*)(ws + o); o += (size_t)32768 * 4;
    size_t fixed = o;

    int Bc = B_N;
    while (Bc > 128 && fixed + 12288ull * Bc > ws_size) Bc >>= 1;

    unsigned short* sa_us = (unsigned short*)(ws + o); o += (size_t)A_N * Bc * 128 * 2;
    unsigned short* se_us = (unsigned short*)(ws + o); o += (size_t)A_N * Bc * 128 * 2;
    unsigned short* ot_us = (unsigned short*)(ws + o); o += (size_t)A_N * Bc * 128 * 2;

    k_zero<<<dim3(18), 256, 0, stream>>>(gsum, 2 * A_N * IN_N);
    k_stats<<<dim3(A_N * 32), 256, 0, stream>>>(obs, actions, gsum, gsq);
    k_finalize<<<dim3(9), 256, 0, stream>>>(gsum, gsq);
    k_wprep<<<dim3(C2E / 256), 256, 0, stream>>>(W_sa, W_s, Wk, Wsel, Wv, Wc1, Wc2,
                                                 gsq, wt_l1, wt_p1, wt_p2, wt_cr, wt_c2);
    k_bfold<<<dim3(A_N), 256, 0, stream>>>(gsum, gsq, W_sa, W_s, b_sa, b_s, fb);

    for (int b0g = 0; b0g < B_N; b0g += Bc) {
        k_l1<<<dim3(Bc / 128, A_N), 512, 0, stream>>>(
            obs, actions, wt_l1, fb, sa_us, se_us, b0g, Bc);
        k_fused<<<dim3(Bc / 4), 256, 0, stream>>>(
            (const unsigned*)sa_us, (const unsigned*)se_us, wt_p1, wt_p2, bv,
            ot_us, Bc);
        k_critic<<<dim3(Bc / 64, A_N), 256, 0, stream>>>(
            (const unsigned*)se_us, (const unsigned*)ot_us, wt_cr, bc1,
            actions, wt_c2, bc2, out, b0g, Bc);
    }
}

// Round 4
// 306.097 us; speedup vs baseline: 1.1005x; 1.1005x over previous
//
#include <hip/hip_runtime.h>
#include <hip/hip_bf16.h>

#define A_N 16
#define B_N 8192
#define O_N 128
#define ACT_N 16
#define H_N 128
#define NH_N 4
#define D_N 32
#define IN_N 144
#define NEGV -1e9f

typedef __attribute__((ext_vector_type(8))) short short8;
typedef __attribute__((ext_vector_type(4))) float floatx4;

// ---- bf16 helpers (RNE) -------------------------------------------------
static __device__ inline unsigned short f2bf(float f) {
    union { float f; unsigned u; } x{f};
    unsigned u = x.u + 0x7FFFu + ((x.u >> 16) & 1u);
    return (unsigned short)(u >> 16);
}
static __device__ inline unsigned pack_bf2(float a, float b) {
    union { float f; unsigned u; } xa{a}, xb{b};
    unsigned ua = xa.u + 0x7FFFu + ((xa.u >> 16) & 1u);
    unsigned ub = xb.u + 0x7FFFu + ((xb.u >> 16) & 1u);
    return (ua >> 16) | (ub & 0xFFFF0000u);
}
static __device__ inline float bf2f(unsigned short h) {
    union { unsigned u; float f; } x;
    x.u = ((unsigned)h) << 16;
    return x.f;
}
static __device__ inline float bflo(unsigned u) {
    union { unsigned u; float f; } x; x.u = u << 16; return x.f;
}
static __device__ inline float bfhi(unsigned u) {
    union { unsigned u; float f; } x; x.u = u & 0xFFFF0000u; return x.f;
}
static __device__ inline short8 ld_frag(const unsigned* p) {
    union { unsigned u[4]; short8 v; } x;
    uint2 lo = *(const uint2*)p;
    uint2 hi = *(const uint2*)(p + 2);
    x.u[0] = lo.x; x.u[1] = lo.y; x.u[2] = hi.x; x.u[3] = hi.y;
    return x.v;
}
static __device__ inline short8 ld_frag4(const unsigned* p) {
    union { uint4 q; short8 v; } x;
    x.q = *(const uint4*)p;
    return x.v;
}

// ---- misc small kernels -------------------------------------------------
__global__ __launch_bounds__(256) void k_zero(float* p, int n) {
    int i = blockIdx.x * 256 + threadIdx.x;
    if (i < n) p[i] = 0.f;
}

__global__ __launch_bounds__(256) void k_stats(const float* __restrict__ obs,
                                               const float* __restrict__ act,
                                               float* __restrict__ gsum,
                                               float* __restrict__ gsq) {
    __shared__ float ssum[IN_N];
    __shared__ float ssq[IN_N];
    int a = blockIdx.x >> 5;
    int r0 = (blockIdx.x & 31) * 256;
    int t = threadIdx.x;
    if (t < IN_N) { ssum[t] = 0.f; ssq[t] = 0.f; }
    __syncthreads();
    if (t < 128) {
        const float* p = obs + ((size_t)a * B_N + r0) * O_N + t;
        float s = 0.f, q = 0.f;
#pragma unroll 4
        for (int r = 0; r < 256; ++r) {
            float v = p[(size_t)r * O_N];
            s += v; q += v * v;
        }
        ssum[t] = s; ssq[t] = q;
    } else {
        int tt = t - 128;
        int f = tt & 15, rg = tt >> 4;
        const float* p = act + ((size_t)a * B_N + r0 + rg) * ACT_N + f;
        float s = 0.f, q = 0.f;
#pragma unroll 4
        for (int i = 0; i < 32; ++i) {
            float v = p[(size_t)i * 8 * ACT_N];
            s += v; q += v * v;
        }
        atomicAdd(&ssum[O_N + f], s);
        atomicAdd(&ssq[O_N + f], q);
    }
    __syncthreads();
    if (t < IN_N) {
        atomicAdd(&gsum[a * IN_N + t], ssum[t]);
        atomicAdd(&gsq[a * IN_N + t], ssq[t]);
    }
}

__global__ __launch_bounds__(256) void k_finalize(float* gsum, float* gsq) {
    int i = blockIdx.x * 256 + threadIdx.x;
    if (i < A_N * IN_N) {
        const float invB = 1.f / (float)B_N;
        float m = gsum[i] * invB;
        float v = fmaxf(gsq[i] * invB - m * m, 0.f);
        gsum[i] = m;
        gsq[i] = rsqrtf(v + 1e-5f);
    }
}

// ---- weight prep: fp32 -> bf16, transposed to [n][k/2] packed uints -----
// wt_l1 rows pre-scaled by rstd (BN folded into weights).
// wt_c2: Wc2 transposed to [a][o][h] fp32 for contiguous critic-tail reads.
#define L1E 393216
#define P1E 409600
#define P2E 417792
#define CRE 679936
#define C2E 712704
__global__ __launch_bounds__(256) void k_wprep(
    const float* __restrict__ W_sa, const float* __restrict__ W_s,
    const float* __restrict__ Wk, const float* __restrict__ Wsel,
    const float* __restrict__ Wv, const float* __restrict__ Wc1,
    const float* __restrict__ Wc2, const float* __restrict__ rstd,
    unsigned* __restrict__ wt_l1, unsigned* __restrict__ wt_p1,
    unsigned* __restrict__ wt_p2, unsigned* __restrict__ wt_cr,
    float* __restrict__ wt_c2) {
    int idx = blockIdx.x * 256 + threadIdx.x;
    if (idx < L1E) {
        int a = idx / 24576, rem = idx % 24576;
        int n = rem & 255, kp = rem >> 8;  // kp 0..95
        int k0 = 2 * kp, k1 = k0 + 1;
        float v0 = 0.f, v1 = 0.f;
        if (n < 128) {
            if (k0 < IN_N) v0 = W_sa[((size_t)a * IN_N + k0) * H_N + n] * rstd[a * IN_N + k0];
            if (k1 < IN_N) v1 = W_sa[((size_t)a * IN_N + k1) * H_N + n] * rstd[a * IN_N + k1];
        } else {
            int m = n - 128;
            if (k0 < O_N) v0 = W_s[((size_t)a * O_N + k0) * H_N + m] * rstd[a * IN_N + k0];
            if (k1 < O_N) v1 = W_s[((size_t)a * O_N + k1) * H_N + m] * rstd[a * IN_N + k1];
        }
        wt_l1[(size_t)a * 24576 + n * 96 + kp] = pack_bf2(v0, v1);
    } else if (idx < P1E) {
        int i2 = idx - L1E;
        int n = i2 & 255, kp = i2 >> 8;
        int k0 = 2 * kp;
        float v0, v1;
        if (n < 128) {
            const float* w = Wk + ((size_t)(n >> 5) * H_N) * D_N + (n & 31);
            v0 = w[(size_t)k0 * D_N]; v1 = w[(size_t)(k0 + 1) * D_N];
        } else {
            int m = n - 128;
            const float* w = Wv + ((size_t)(m >> 5) * H_N) * D_N + (m & 31);
            v0 = w[(size_t)k0 * D_N]; v1 = w[(size_t)(k0 + 1) * D_N];
        }
        wt_p1[n * 64 + kp] = pack_bf2(v0, v1);
    } else if (idx < P2E) {
        int i3 = idx - P1E;
        int n = i3 & 127, kp = i3 >> 7;
        int k0 = 2 * kp;
        const float* w = Wsel + ((size_t)(n >> 5) * H_N) * D_N + (n & 31);
        wt_p2[n * 64 + kp] = pack_bf2(w[(size_t)k0 * D_N], w[(size_t)(k0 + 1) * D_N]);
    } else if (idx < CRE) {
        int i4 = idx - P2E;
        int a = i4 >> 14, r = i4 & 16383;
        int n = r & 127, kp = r >> 7;
        int k0 = 2 * kp;
        const float* w = Wc1 + (size_t)a * 256 * H_N + n;
        wt_cr[(size_t)a * 16384 + n * 128 + kp] =
            pack_bf2(w[(size_t)k0 * H_N], w[(size_t)(k0 + 1) * H_N]);
    } else if (idx < C2E) {
        int i5 = idx - CRE;
        int a = i5 >> 11, rem = i5 & 2047;
        int oo = rem >> 7, h = rem & 127;
        wt_c2[i5] = Wc2[((size_t)a * H_N + h) * ACT_N + oo];
    }
}

// ---- folded biases: fb[0][a][c] = b_sa - sum(m*r*W_sa); fb[1] for se ----
__global__ __launch_bounds__(256) void k_bfold(
    const float* __restrict__ mean, const float* __restrict__ rstd,
    const float* __restrict__ W_sa, const float* __restrict__ W_s,
    const float* __restrict__ b_sa, const float* __restrict__ b_s,
    float* __restrict__ fb) {
    int a = blockIdx.x, c = threadIdx.x;
    float s = 0.f;
    if (c < 128) {
        for (int k = 0; k < IN_N; ++k)
            s += mean[a * IN_N + k] * rstd[a * IN_N + k] *
                 W_sa[((size_t)a * IN_N + k) * H_N + c];
        fb[a * 128 + c] = b_sa[a * H_N + c] - s;
    } else {
        int m = c - 128;
        for (int k = 0; k < O_N; ++k)
            s += mean[a * IN_N + k] * rstd[a * IN_N + k] *
                 W_s[((size_t)a * O_N + k) * H_N + m];
        fb[2048 + a * 128 + m] = b_s[a * H_N + m] - s;
    }
}

// ---- L1 merged: one block does BOTH sa (cols 0-127) and se (128-255). ---
// T14: chunk c+1 X loads issued before chunk c MFMA, written after barrier.
__global__ __launch_bounds__(512, 2) void k_l1(
    const float* __restrict__ obs, const float* __restrict__ act,
    const unsigned* __restrict__ wt_l1, const float* __restrict__ fb,
    unsigned short* __restrict__ sa_us, unsigned short* __restrict__ se_us,
    int b0g, int Bc) {
    __shared__ unsigned smem[(128 + 256) * 34];
    unsigned* Xs = smem;
    unsigned* Ws = smem + 128 * 34;

    int a = blockIdx.y;
    int b0 = blockIdx.x * 128;
    int t = threadIdx.x;
    int wid = t >> 6, lane = t & 63, lm = lane & 15, lq = lane >> 4;
    int wrow = (wid & 1) * 64;
    int wcol = (wid >> 1) * 64;  // 0,64 -> sa; 128,192 -> se

    floatx4 acc[4][4];
#pragma unroll
    for (int mt = 0; mt < 4; ++mt)
#pragma unroll
        for (int nt = 0; nt < 4; ++nt)
#pragma unroll
            for (int e = 0; e < 4; ++e) acc[mt][nt][e] = 0.f;

    const unsigned* WtA = wt_l1 + (size_t)a * 24576;

    float4 xr[4];
    auto loadx = [&](int cc) {
#pragma unroll
        for (int i = 0; i < 4; ++i) {
            int idx = t + i * 512;
            int r = idx >> 4, c4 = idx & 15;
            int k = cc * 64 + c4 * 4;
            size_t grow = (size_t)a * B_N + b0g + b0 + r;
            if (k < O_N) xr[i] = *(const float4*)&obs[grow * O_N + k];
            else if (k < IN_N) xr[i] = *(const float4*)&act[grow * ACT_N + (k - O_N)];
            else xr[i] = make_float4(0.f, 0.f, 0.f, 0.f);
        }
    };
    auto writex = [&]() {
#pragma unroll
        for (int i = 0; i < 4; ++i) {
            int idx = t + i * 512;
            int r = idx >> 4, c4 = idx & 15;
            uint2* dst = (uint2*)&Xs[r * 34 + c4 * 2];
            *dst = make_uint2(pack_bf2(xr[i].x, xr[i].y), pack_bf2(xr[i].z, xr[i].w));
        }
    };
    auto stagew = [&](int cc) {
#pragma unroll
        for (int i = 0; i < 4; ++i) {
            int idx = t + i * 512;
            int n = idx >> 3, c4 = idx & 7;
            uint4 w = *(const uint4*)&WtA[(size_t)n * 96 + cc * 32 + c4 * 4];
            uint2* dst = (uint2*)&Ws[n * 34 + c4 * 4];
            dst[0] = make_uint2(w.x, w.y);
            dst[1] = make_uint2(w.z, w.w);
        }
    };

    loadx(0);
    writex();
    stagew(0);
    __syncthreads();

    for (int c = 0; c < 3; ++c) {
        if (c < 2) loadx(c + 1);  // T14: in flight during MFMA
#pragma unroll
        for (int s = 0; s < 2; ++s) {
            if (c * 64 + s * 32 >= 160) break;
            short8 afr[4];
#pragma unroll
            for (int mt = 0; mt < 4; ++mt)
                afr[mt] = ld_frag(&Xs[(wrow + mt * 16 + lm) * 34 + s * 16 + lq * 4]);
#pragma unroll
            for (int nt = 0; nt < 4; ++nt) {
                short8 bfr = ld_frag(&Ws[(wcol + nt * 16 + lm) * 34 + s * 16 + lq * 4]);
#pragma unroll
                for (int mt = 0; mt < 4; ++mt)
                    acc[mt][nt] = __builtin_amdgcn_mfma_f32_16x16x32_bf16(
                        afr[mt], bfr, acc[mt][nt], 0, 0, 0);
            }
        }
        __syncthreads();
        if (c < 2) {
            writex();
            stagew(c + 1);
            __syncthreads();
        }
    }

    int zsel = (wcol >= 128);
    unsigned short* outp = zsel ? se_us : sa_us;
    const float* bias = fb + zsel * 2048 + a * 128;
    int cbase = wcol & 127;
#pragma unroll
    for (int mt = 0; mt < 4; ++mt)
#pragma unroll
        for (int nt = 0; nt < 4; ++nt)
#pragma unroll
            for (int r = 0; r < 4; ++r) {
                int row = wrow + mt * 16 + lq * 4 + r;
                int col = cbase + nt * 16 + lm;
                float v = acc[mt][nt][r] + bias[col];
                v = v > 0.f ? v : 0.01f * v;
                outp[((size_t)(b0 + row) * 16 + a) * 128 + col] = f2bf(v);
            }
}

// ---- fused: keys|vals (ONE N=256 pass) + sel GEMM + MFMA QK^T + PV ------
// batch-major; wave tile 64x64 in kv pass: 16 B-frags in flight, 64 MFMAs
// per phase. se rows prefetched to regs before kv (T14). Tail = R2.
__global__ __launch_bounds__(256, 3) void k_fused(
    const unsigned* __restrict__ sa_u, const unsigned* __restrict__ se_u,
    const unsigned* __restrict__ wt_p1, const unsigned* __restrict__ wt_p2,
    const float* __restrict__ bv, unsigned short* __restrict__ other_us,
    int Bc) {
    __shared__ unsigned Xs[64 * 66];            // 16896 B (sa/se, then sel)
    __shared__ unsigned short keys_s[64 * 130]; // 16640 B (lg after QK^T)
    __shared__ unsigned short vals_s[64 * 136]; // 17408 B (16B-aligned rows)
    unsigned short* sel_s = (unsigned short*)Xs;

    int bg0 = blockIdx.x * 4;
    int t = threadIdx.x;
    int wid = t >> 6, lane = t & 63, lm = lane & 15, lq = lane >> 4;

    const unsigned* sa_base = sa_u + (size_t)(bg0 * 16) * 64;
    const unsigned* se_base = se_u + (size_t)(bg0 * 16) * 64;

    // ---- stage sa: 64 contiguous rows, linear uint4 stream ----
    for (int idx = t; idx < 64 * 16; idx += 256) {
        int r = idx >> 4, c4 = idx & 15;
        uint4 v = *(const uint4*)&sa_base[(size_t)idx * 4];
        uint2* dst = (uint2*)&Xs[r * 66 + c4 * 4];
        dst[0] = make_uint2(v.x, v.y);
        dst[1] = make_uint2(v.z, v.w);
    }
    // ---- issue se loads NOW; they land after the kv phase ----
    uint4 seR[4];
#pragma unroll
    for (int ii = 0; ii < 4; ++ii)
        seR[ii] = *(const uint4*)&se_base[(size_t)(t + ii * 256) * 4];
    __syncthreads();

    // ---- merged keys|vals GEMM: N=256, wave = 64 rows x 64 cols ----
    {
        floatx4 acc[4][4];
#pragma unroll
        for (int mt = 0; mt < 4; ++mt)
#pragma unroll
            for (int nt = 0; nt < 4; ++nt)
#pragma unroll
                for (int e = 0; e < 4; ++e) acc[mt][nt][e] = 0.f;
#pragma unroll
        for (int s = 0; s < 4; ++s) {
            short8 afr[4];
#pragma unroll
            for (int mt = 0; mt < 4; ++mt)
                afr[mt] = ld_frag(&Xs[(mt * 16 + lm) * 66 + s * 16 + lq * 4]);
#pragma unroll
            for (int nt = 0; nt < 4; ++nt) {
                int col = wid * 64 + nt * 16 + lm;  // 0..255 (keys|vals)
                short8 bfr = ld_frag4(wt_p1 + (size_t)col * 64 + s * 16 + lq * 4);
#pragma unroll
                for (int mt = 0; mt < 4; ++mt)
                    acc[mt][nt] = __builtin_amdgcn_mfma_f32_16x16x32_bf16(
                        afr[mt], bfr, acc[mt][nt], 0, 0, 0);
            }
        }
        if (wid < 2) {  // keys cols 0..127
#pragma unroll
            for (int mt = 0; mt < 4; ++mt)
#pragma unroll
                for (int nt = 0; nt < 4; ++nt)
#pragma unroll
                    for (int r = 0; r < 4; ++r) {
                        int row = mt * 16 + lq * 4 + r;
                        int col = wid * 64 + nt * 16 + lm;
                        keys_s[row * 130 + col] = f2bf(acc[mt][nt][r]);
                    }
        } else {  // vals cols 0..127 (+bias, lrelu)
#pragma unroll
            for (int mt = 0; mt < 4; ++mt)
#pragma unroll
                for (int nt = 0; nt < 4; ++nt) {
                    int col = (wid - 2) * 64 + nt * 16 + lm;
                    float bvc = bv[col];
#pragma unroll
                    for (int r = 0; r < 4; ++r) {
                        int row = mt * 16 + lq * 4 + r;
                        float v = acc[mt][nt][r] + bvc;
                        v = v > 0.f ? v : 0.01f * v;
                        vals_s[row * 136 + col] = f2bf(v);
                    }
                }
        }
    }
    __syncthreads();

    // ---- write prefetched se rows (overwrite sa) ----
#pragma unroll
    for (int ii = 0; ii < 4; ++ii) {
        int idx = t + ii * 256;
        int r = idx >> 4, c4 = idx & 15;
        uint2* dst = (uint2*)&Xs[r * 66 + c4 * 4];
        dst[0] = make_uint2(seR[ii].x, seR[ii].y);
        dst[1] = make_uint2(seR[ii].z, seR[ii].w);
    }
    __syncthreads();

    // ---- GEMM2: sel (wave = 64 rows x 32 cols) ----
    {
        int wcol = wid * 32;
        floatx4 acc[4][2];
#pragma unroll
        for (int mt = 0; mt < 4; ++mt)
#pragma unroll
            for (int nt = 0; nt < 2; ++nt)
#pragma unroll
                for (int e = 0; e < 4; ++e) acc[mt][nt][e] = 0.f;
#pragma unroll
        for (int s = 0; s < 4; ++s) {
            short8 afr[4];
#pragma unroll
            for (int mt = 0; mt < 4; ++mt)
                afr[mt] = ld_frag(&Xs[(mt * 16 + lm) * 66 + s * 16 + lq * 4]);
#pragma unroll
            for (int nt = 0; nt < 2; ++nt) {
                int col = wcol + nt * 16 + lm;
                short8 bfr = ld_frag4(wt_p2 + (size_t)col * 64 + s * 16 + lq * 4);
#pragma unroll
                for (int mt = 0; mt < 4; ++mt)
                    acc[mt][nt] = __builtin_amdgcn_mfma_f32_16x16x32_bf16(
                        afr[mt], bfr, acc[mt][nt], 0, 0, 0);
            }
        }
        __syncthreads();  // all waves done reading Xs(se)
#pragma unroll
        for (int mt = 0; mt < 4; ++mt)
#pragma unroll
            for (int nt = 0; nt < 2; ++nt)
#pragma unroll
                for (int r = 0; r < 4; ++r) {
                    int row = mt * 16 + lq * 4 + r;
                    int col = wcol + nt * 16 + lm;
                    sel_s[row * 132 + col] = f2bf(acc[mt][nt][r]);
                }
    }
    __syncthreads();

    // ---- QK^T via MFMA: wave wid = bsub; one mfma per head n ----
    const unsigned* keysU = (const unsigned*)keys_s;
    floatx4 lgacc[4];
#pragma unroll
    for (int n = 0; n < 4; ++n) {
        short8 af = ld_frag(&Xs[(wid * 16 + lm) * 66 + n * 16 + lq * 4]);     // sel
        short8 bf = ld_frag(&keysU[(wid * 16 + lm) * 65 + n * 16 + lq * 4]);  // keys
        floatx4 z4 = {0.f, 0.f, 0.f, 0.f};
        lgacc[n] = __builtin_amdgcn_mfma_f32_16x16x32_bf16(af, bf, z4, 0, 0, 0);
    }
    __syncthreads();  // keys reads complete everywhere; reuse region for lg

    // lg layout: [(bsub*4+n)*16 + i][16 j] fp32 (16 KB in keys region)
    float* lgs = (float*)keys_s;
#pragma unroll
    for (int n = 0; n < 4; ++n)
#pragma unroll
        for (int r = 0; r < 4; ++r) {
            int i = lq * 4 + r;
            lgs[((wid * 4 + n) * 16 + i) * 16 + lm] =
                lgacc[n][r] * 0.17677669529663687f;
        }
    // wave-local readback (DS ops in-order per wave)

    int bsub = wid, n = (t >> 4) & 3, i = t & 15;
    float lg[16];
    {
        const float4* lgp = (const float4*)&lgs[((bsub * 4 + n) * 16 + i) * 16];
#pragma unroll
        for (int c = 0; c < 4; ++c) {
            float4 v = lgp[c];
            lg[4 * c] = v.x; lg[4 * c + 1] = v.y;
            lg[4 * c + 2] = v.z; lg[4 * c + 3] = v.w;
        }
    }
    lg[i] = NEGV;
    float m = lg[0];
#pragma unroll
    for (int j = 1; j < 16; ++j) m = fmaxf(m, lg[j]);
    float sum = 0.f;
#pragma unroll
    for (int j = 0; j < 16; ++j) { lg[j] = __expf(lg[j] - m); sum += lg[j]; }
    float inv = 1.f / sum;
#pragma unroll
    for (int j = 0; j < 16; ++j) lg[j] *= inv;

    // ---- PV: vals row for (agent j, bsub) = bsub*16 + j ----
    const unsigned* valsU = (const unsigned*)vals_s;
    float ov[32];
#pragma unroll
    for (int u = 0; u < 32; ++u) ov[u] = 0.f;
#pragma unroll
    for (int j = 0; j < 16; ++j) {
        const uint4* vrow = (const uint4*)&valsU[(bsub * 16 + j) * 68 + n * 16];
        float w = lg[j];
#pragma unroll
        for (int c = 0; c < 4; ++c) {
            uint4 x = vrow[c];
            ov[8 * c + 0] = fmaf(w, bflo(x.x), ov[8 * c + 0]);
            ov[8 * c + 1] = fmaf(w, bfhi(x.x), ov[8 * c + 1]);
            ov[8 * c + 2] = fmaf(w, bflo(x.y), ov[8 * c + 2]);
            ov[8 * c + 3] = fmaf(w, bfhi(x.y), ov[8 * c + 3]);
            ov[8 * c + 4] = fmaf(w, bflo(x.z), ov[8 * c + 4]);
            ov[8 * c + 5] = fmaf(w, bfhi(x.z), ov[8 * c + 5]);
            ov[8 * c + 6] = fmaf(w, bflo(x.w), ov[8 * c + 6]);
            ov[8 * c + 7] = fmaf(w, bfhi(x.w), ov[8 * c + 7]);
        }
    }
    {
        uint4* orow = (uint4*)&other_us[((size_t)(bg0 + bsub) * 16 + i) * 128 + n * 32];
#pragma unroll
        for (int h = 0; h < 2; ++h) {
            uint4 o;
            o.x = pack_bf2(ov[16 * h + 0], ov[16 * h + 1]);
            o.y = pack_bf2(ov[16 * h + 2], ov[16 * h + 3]);
            o.z = pack_bf2(ov[16 * h + 4], ov[16 * h + 5]);
            o.w = pack_bf2(ov[16 * h + 6], ov[16 * h + 7]);
            orow[2 * h] = o;
            o.x = pack_bf2(ov[16 * h + 8], ov[16 * h + 9]);
            o.y = pack_bf2(ov[16 * h + 10], ov[16 * h + 11]);
            o.z = pack_bf2(ov[16 * h + 12], ov[16 * h + 13]);
            o.w = pack_bf2(ov[16 * h + 14], ov[16 * h + 15]);
            orow[2 * h + 1] = o;
        }
    }
}

// ---- critic: block 64 rows x 128 cols, wave 32x64, acc[2][4] ------------
// T14 reg-prefetch: chunk c+1's X/W global loads in flight during c's MFMA.
__global__ __launch_bounds__(256, 4) void k_critic(
    const unsigned* __restrict__ se_u, const unsigned* __restrict__ other_u,
    const unsigned* __restrict__ wt_cr,
    const float* __restrict__ bc1, const float* __restrict__ actions,
    const float* __restrict__ wt_c2, const float* __restrict__ bc2,
    float* __restrict__ qout, int b0g, int Bc) {
    __shared__ unsigned smem[(64 + 128) * 34];
    unsigned* Xs = smem;
    unsigned* Ws = smem + 64 * 34;

    int a = blockIdx.y;
    int b0 = blockIdx.x * 64;
    int t = threadIdx.x;
    int wid = t >> 6, lane = t & 63, lm = lane & 15, lq = lane >> 4;
    int wrow = (wid & 1) * 32;
    int wcol = (wid >> 1) * 64;

    floatx4 acc[2][4];
#pragma unroll
    for (int mt = 0; mt < 2; ++mt)
#pragma unroll
        for (int nt = 0; nt < 4; ++nt)
#pragma unroll
            for (int e = 0; e < 4; ++e) acc[mt][nt][e] = 0.f;

    const unsigned* WtA = wt_cr + (size_t)a * 16384;

    uint4 xr[2], wr[4];
    auto loadxw = [&](int cc) {
        const unsigned* src = (cc < 2) ? se_u : other_u;
        int off = (cc & 1) * 32;
#pragma unroll
        for (int i = 0; i < 2; ++i) {
            int idx = t + i * 256;
            int r = idx >> 3, c4 = idx & 7;
            xr[i] = *(const uint4*)&src[((size_t)(b0 + r) * 16 + a) * 64 + off + c4 * 4];
        }
#pragma unroll
        for (int i = 0; i < 4; ++i) {
            int idx = t + i * 256;
            int n = idx >> 3, c4 = idx & 7;
            wr[i] = *(const uint4*)&WtA[(size_t)n * 128 + cc * 32 + c4 * 4];
        }
    };
    auto writexw = [&]() {
#pragma unroll
        for (int i = 0; i < 2; ++i) {
            int idx = t + i * 256;
            int r = idx >> 3, c4 = idx & 7;
            uint2* dst = (uint2*)&Xs[r * 34 + c4 * 4];
            dst[0] = make_uint2(xr[i].x, xr[i].y);
            dst[1] = make_uint2(xr[i].z, xr[i].w);
        }
#pragma unroll
        for (int i = 0; i < 4; ++i) {
            int idx = t + i * 256;
            int n = idx >> 3, c4 = idx & 7;
            uint2* dst = (uint2*)&Ws[n * 34 + c4 * 4];
            dst[0] = make_uint2(wr[i].x, wr[i].y);
            dst[1] = make_uint2(wr[i].z, wr[i].w);
        }
    };

    loadxw(0);
    writexw();
    __syncthreads();

    for (int c = 0; c < 4; ++c) {
        if (c < 3) loadxw(c + 1);  // T14: in flight during MFMA
#pragma unroll
        for (int s = 0; s < 2; ++s) {
            short8 afr[2];
#pragma unroll
            for (int mt = 0; mt < 2; ++mt)
                afr[mt] = ld_frag(&Xs[(wrow + mt * 16 + lm) * 34 + s * 16 + lq * 4]);
#pragma unroll
            for (int nt = 0; nt < 4; ++nt) {
                short8 bfr = ld_frag(&Ws[(wcol + nt * 16 + lm) * 34 + s * 16 + lq * 4]);
#pragma unroll
                for (int mt = 0; mt < 2; ++mt)
                    acc[mt][nt] = __builtin_amdgcn_mfma_f32_16x16x32_bf16(
                        afr[mt], bfr, acc[mt][nt], 0, 0, 0);
            }
        }
        __syncthreads();
        if (c < 3) {
            writexw();
            __syncthreads();
        }
    }

    unsigned short* hbuf = (unsigned short*)smem;  // [64][132]
#pragma unroll
    for (int mt = 0; mt < 2; ++mt)
#pragma unroll
        for (int nt = 0; nt < 4; ++nt)
#pragma unroll
            for (int r = 0; r < 4; ++r) {
                int row = wrow + mt * 16 + lq * 4 + r;
                int col = wcol + nt * 16 + lm;
                float v = acc[mt][nt][r] + bc1[a * H_N + col];
                v = v > 0.f ? v : 0.01f * v;
                hbuf[row * 132 + col] = f2bf(v);
            }
    __syncthreads();
    if (t < 64) {
        size_t arow = (size_t)a * B_N + b0g + b0 + t;
        const float* ap = &actions[arow * ACT_N];
        float bestv = ap[0];
        int bi = 0;
        for (int o = 1; o < ACT_N; ++o) {
            float v = ap[o];
            if (v > bestv) { bestv = v; bi = o; }
        }
        float q = bc2[a * ACT_N + bi];
        const float4* w4p = (const float4*)&wt_c2[((size_t)a * ACT_N + bi) * H_N];
        const uint2* hp2 = (const uint2*)&hbuf[t * 132];
#pragma unroll
        for (int h4 = 0; h4 < 32; ++h4) {
            float4 w4 = w4p[h4];
            uint2 hh = hp2[h4];
            q = fmaf(bflo(hh.x), w4.x, q);
            q = fmaf(bfhi(hh.x), w4.y, q);
            q = fmaf(bflo(hh.y), w4.z, q);
            q = fmaf(bfhi(hh.y), w4.w, q);
        }
        qout[arow] = q;
    }
}

extern "C" void kernel_launch(void* const* d_in, const int* in_sizes, int n_in,
                              void* d_out, int out_size, void* d_ws, size_t ws_size,
                              hipStream_t stream) {
    const float* obs     = (const float*)d_in[0];
    const float* actions = (const float*)d_in[1];
    const float* W_sa    = (const float*)d_in[2];
    const float* b_sa    = (const float*)d_in[3];
    const float* W_s     = (const float*)d_in[4];
    const float* b_s     = (const float*)d_in[5];
    const float* Wk      = (const float*)d_in[6];
    const float* Wsel    = (const float*)d_in[7];
    const float* Wv      = (const float*)d_in[8];
    const float* bv      = (const float*)d_in[9];
    const float* Wc1     = (const float*)d_in[10];
    const float* bc1     = (const float*)d_in[11];
    const float* Wc2     = (const float*)d_in[12];
    const float* bc2     = (const float*)d_in[13];
    float* out = (float*)d_out;
    char* ws = (char*)d_ws;

    size_t o = 0;
    float* gsum = (float*)(ws + o); o += 2304 * 4;
    float* gsq  = (float*)(ws + o); o += 2304 * 4;
    unsigned* wt_l1 = (unsigned*)(ws + o); o += (size_t)393216 * 4;
    unsigned* wt_p1 = (unsigned*)(ws + o); o += (size_t)16384 * 4;
    unsigned* wt_p2 = (unsigned*)(ws + o); o += (size_t)8192 * 4;
    unsigned* wt_cr = (unsigned*)(ws + o); o += (size_t)262144 * 4;
    float* fb = (float*)(ws + o); o += (size_t)4096 * 4;
    float* wt_c2 = (float*)(ws + o); o += (size_t)32768 * 4;
    size_t fixed = o;

    int Bc = B_N;
    while (Bc > 128 && fixed + 12288ull * Bc > ws_size) Bc >>= 1;

    unsigned short* sa_us = (unsigned short*)(ws + o); o += (size_t)A_N * Bc * 128 * 2;
    unsigned short* se_us = (unsigned short*)(ws + o); o += (size_t)A_N * Bc * 128 * 2;
    unsigned short* ot_us = (unsigned short*)(ws + o); o += (size_t)A_N * Bc * 128 * 2;

    k_zero<<<dim3(18), 256, 0, stream>>>(gsum, 2 * A_N * IN_N);
    k_stats<<<dim3(A_N * 32), 256, 0, stream>>>(obs, actions, gsum, gsq);
    k_finalize<<<dim3(9), 256, 0, stream>>>(gsum, gsq);
    k_wprep<<<dim3(C2E / 256), 256, 0, stream>>>(W_sa, W_s, Wk, Wsel, Wv, Wc1, Wc2,
                                                 gsq, wt_l1, wt_p1, wt_p2, wt_cr, wt_c2);
    k_bfold<<<dim3(A_N), 256, 0, stream>>>(gsum, gsq, W_sa, W_s, b_sa, b_s, fb);

    for (int b0g = 0; b0g < B_N; b0g += Bc) {
        k_l1<<<dim3(Bc / 128, A_N), 512, 0, stream>>>(
            obs, actions, wt_l1, fb, sa_us, se_us, b0g, Bc);
        k_fused<<<dim3(Bc / 4), 256, 0, stream>>>(
            (const unsigned*)sa_us, (const unsigned*)se_us, wt_p1, wt_p2, bv,
            ot_us, Bc);
        k_critic<<<dim3(Bc / 64, A_N), 256, 0, stream>>>(
            (const unsigned*)se_us, (const unsigned*)ot_us, wt_cr, bc1,
            actions, wt_c2, bc2, out, b0g, Bc);
    }
}

// Round 5
// 299.446 us; speedup vs baseline: 1.1249x; 1.0222x over previous
//
#include <hip/hip_runtime.h>
#include <hip/hip_bf16.h>

#define A_N 16
#define B_N 8192
#define O_N 128
#define ACT_N 16
#define H_N 128
#define NH_N 4
#define D_N 32
#define IN_N 144
#define NEGV -1e9f

typedef __attribute__((ext_vector_type(8))) short short8;
typedef __attribute__((ext_vector_type(4))) float floatx4;

// ---- bf16 helpers (RNE) -------------------------------------------------
static __device__ inline unsigned short f2bf(float f) {
    union { float f; unsigned u; } x{f};
    unsigned u = x.u + 0x7FFFu + ((x.u >> 16) & 1u);
    return (unsigned short)(u >> 16);
}
static __device__ inline unsigned pack_bf2(float a, float b) {
    union { float f; unsigned u; } xa{a}, xb{b};
    unsigned ua = xa.u + 0x7FFFu + ((xa.u >> 16) & 1u);
    unsigned ub = xb.u + 0x7FFFu + ((xb.u >> 16) & 1u);
    return (ua >> 16) | (ub & 0xFFFF0000u);
}
static __device__ inline float bf2f(unsigned short h) {
    union { unsigned u; float f; } x;
    x.u = ((unsigned)h) << 16;
    return x.f;
}
static __device__ inline float bflo(unsigned u) {
    union { unsigned u; float f; } x; x.u = u << 16; return x.f;
}
static __device__ inline float bfhi(unsigned u) {
    union { unsigned u; float f; } x; x.u = u & 0xFFFF0000u; return x.f;
}
static __device__ inline short8 ld_frag(const unsigned* p) {
    union { unsigned u[4]; short8 v; } x;
    uint2 lo = *(const uint2*)p;
    uint2 hi = *(const uint2*)(p + 2);
    x.u[0] = lo.x; x.u[1] = lo.y; x.u[2] = hi.x; x.u[3] = hi.y;
    return x.v;
}
static __device__ inline short8 ld_frag4(const unsigned* p) {
    union { uint4 q; short8 v; } x;
    x.q = *(const uint4*)p;
    return x.v;
}

// ---- misc small kernels -------------------------------------------------
__global__ __launch_bounds__(256) void k_zero(float* p, int n) {
    int i = blockIdx.x * 256 + threadIdx.x;
    if (i < n) p[i] = 0.f;
}

// 256 blocks: (agent, 512-row slab). All 256 threads do float4 obs reads.
__global__ __launch_bounds__(256) void k_stats(const float* __restrict__ obs,
                                               const float* __restrict__ act,
                                               float* __restrict__ gsum,
                                               float* __restrict__ gsq) {
    __shared__ float ssum[IN_N];
    __shared__ float ssq[IN_N];
    int a = blockIdx.x >> 4;
    int r0 = (blockIdx.x & 15) * 512;
    int t = threadIdx.x;
    if (t < IN_N) { ssum[t] = 0.f; ssq[t] = 0.f; }
    __syncthreads();
    {
        int c0 = (t & 31) * 4, rg = t >> 5;  // 8 row-groups x 32 col-quads
        const float* p = obs + ((size_t)a * B_N + r0 + rg) * O_N + c0;
        float s0 = 0.f, s1 = 0.f, s2 = 0.f, s3 = 0.f;
        float q0 = 0.f, q1 = 0.f, q2 = 0.f, q3 = 0.f;
#pragma unroll 4
        for (int i = 0; i < 64; ++i) {
            float4 v = *(const float4*)(p + (size_t)i * 8 * O_N);
            s0 += v.x; q0 += v.x * v.x;
            s1 += v.y; q1 += v.y * v.y;
            s2 += v.z; q2 += v.z * v.z;
            s3 += v.w; q3 += v.w * v.w;
        }
        atomicAdd(&ssum[c0 + 0], s0); atomicAdd(&ssq[c0 + 0], q0);
        atomicAdd(&ssum[c0 + 1], s1); atomicAdd(&ssq[c0 + 1], q1);
        atomicAdd(&ssum[c0 + 2], s2); atomicAdd(&ssq[c0 + 2], q2);
        atomicAdd(&ssum[c0 + 3], s3); atomicAdd(&ssq[c0 + 3], q3);
    }
    if (t < 128) {
        int f = t & 15, rg = t >> 4;  // 8 row-groups x 16 features
        const float* p = act + ((size_t)a * B_N + r0 + rg) * ACT_N + f;
        float s = 0.f, q = 0.f;
#pragma unroll 4
        for (int i = 0; i < 64; ++i) {
            float v = p[(size_t)i * 8 * ACT_N];
            s += v; q += v * v;
        }
        atomicAdd(&ssum[O_N + f], s);
        atomicAdd(&ssq[O_N + f], q);
    }
    __syncthreads();
    if (t < IN_N) {
        atomicAdd(&gsum[a * IN_N + t], ssum[t]);
        atomicAdd(&gsq[a * IN_N + t], ssq[t]);
    }
}

__global__ __launch_bounds__(256) void k_finalize(float* gsum, float* gsq) {
    int i = blockIdx.x * 256 + threadIdx.x;
    if (i < A_N * IN_N) {
        const float invB = 1.f / (float)B_N;
        float m = gsum[i] * invB;
        float v = fmaxf(gsq[i] * invB - m * m, 0.f);
        gsum[i] = m;
        gsq[i] = rsqrtf(v + 1e-5f);
    }
}

// ---- weight prep: fp32 -> bf16, transposed to [n][k/2] packed uints -----
// wt_l1 rows pre-scaled by rstd (BN folded into weights).
// wt_c2: Wc2 transposed to [a][o][h] fp32 for contiguous critic-tail reads.
#define L1E 393216
#define P1E 409600
#define P2E 417792
#define CRE 679936
#define C2E 712704
__global__ __launch_bounds__(256) void k_wprep(
    const float* __restrict__ W_sa, const float* __restrict__ W_s,
    const float* __restrict__ Wk, const float* __restrict__ Wsel,
    const float* __restrict__ Wv, const float* __restrict__ Wc1,
    const float* __restrict__ Wc2, const float* __restrict__ rstd,
    unsigned* __restrict__ wt_l1, unsigned* __restrict__ wt_p1,
    unsigned* __restrict__ wt_p2, unsigned* __restrict__ wt_cr,
    float* __restrict__ wt_c2) {
    int idx = blockIdx.x * 256 + threadIdx.x;
    if (idx < L1E) {
        int a = idx / 24576, rem = idx % 24576;
        int n = rem & 255, kp = rem >> 8;  // kp 0..95
        int k0 = 2 * kp, k1 = k0 + 1;
        float v0 = 0.f, v1 = 0.f;
        if (n < 128) {
            if (k0 < IN_N) v0 = W_sa[((size_t)a * IN_N + k0) * H_N + n] * rstd[a * IN_N + k0];
            if (k1 < IN_N) v1 = W_sa[((size_t)a * IN_N + k1) * H_N + n] * rstd[a * IN_N + k1];
        } else {
            int m = n - 128;
            if (k0 < O_N) v0 = W_s[((size_t)a * O_N + k0) * H_N + m] * rstd[a * IN_N + k0];
            if (k1 < O_N) v1 = W_s[((size_t)a * O_N + k1) * H_N + m] * rstd[a * IN_N + k1];
        }
        wt_l1[(size_t)a * 24576 + n * 96 + kp] = pack_bf2(v0, v1);
    } else if (idx < P1E) {
        int i2 = idx - L1E;
        int n = i2 & 255, kp = i2 >> 8;
        int k0 = 2 * kp;
        float v0, v1;
        if (n < 128) {
            const float* w = Wk + ((size_t)(n >> 5) * H_N) * D_N + (n & 31);
            v0 = w[(size_t)k0 * D_N]; v1 = w[(size_t)(k0 + 1) * D_N];
        } else {
            int m = n - 128;
            const float* w = Wv + ((size_t)(m >> 5) * H_N) * D_N + (m & 31);
            v0 = w[(size_t)k0 * D_N]; v1 = w[(size_t)(k0 + 1) * D_N];
        }
        wt_p1[n * 64 + kp] = pack_bf2(v0, v1);
    } else if (idx < P2E) {
        int i3 = idx - P1E;
        int n = i3 & 127, kp = i3 >> 7;
        int k0 = 2 * kp;
        const float* w = Wsel + ((size_t)(n >> 5) * H_N) * D_N + (n & 31);
        wt_p2[n * 64 + kp] = pack_bf2(w[(size_t)k0 * D_N], w[(size_t)(k0 + 1) * D_N]);
    } else if (idx < CRE) {
        int i4 = idx - P2E;
        int a = i4 >> 14, r = i4 & 16383;
        int n = r & 127, kp = r >> 7;
        int k0 = 2 * kp;
        const float* w = Wc1 + (size_t)a * 256 * H_N + n;
        wt_cr[(size_t)a * 16384 + n * 128 + kp] =
            pack_bf2(w[(size_t)k0 * H_N], w[(size_t)(k0 + 1) * H_N]);
    } else if (idx < C2E) {
        int i5 = idx - CRE;
        int a = i5 >> 11, rem = i5 & 2047;
        int oo = rem >> 7, h = rem & 127;
        wt_c2[i5] = Wc2[((size_t)a * H_N + h) * ACT_N + oo];
    }
}

// ---- folded biases: fb[0][a][c] = b_sa - sum(m*r*W_sa); fb[1] for se ----
__global__ __launch_bounds__(256) void k_bfold(
    const float* __restrict__ mean, const float* __restrict__ rstd,
    const float* __restrict__ W_sa, const float* __restrict__ W_s,
    const float* __restrict__ b_sa, const float* __restrict__ b_s,
    float* __restrict__ fb) {
    int a = blockIdx.x, c = threadIdx.x;
    float s = 0.f;
    if (c < 128) {
        for (int k = 0; k < IN_N; ++k)
            s += mean[a * IN_N + k] * rstd[a * IN_N + k] *
                 W_sa[((size_t)a * IN_N + k) * H_N + c];
        fb[a * 128 + c] = b_sa[a * H_N + c] - s;
    } else {
        int m = c - 128;
        for (int k = 0; k < O_N; ++k)
            s += mean[a * IN_N + k] * rstd[a * IN_N + k] *
                 W_s[((size_t)a * O_N + k) * H_N + m];
        fb[2048 + a * 128 + m] = b_s[a * H_N + m] - s;
    }
}

// ---- L1 merged (R3-proven body): one block does sa AND se. --------------
__global__ __launch_bounds__(512, 2) void k_l1(
    const float* __restrict__ obs, const float* __restrict__ act,
    const unsigned* __restrict__ wt_l1, const float* __restrict__ fb,
    unsigned short* __restrict__ sa_us, unsigned short* __restrict__ se_us,
    int b0g, int Bc) {
    __shared__ unsigned smem[(128 + 256) * 34];
    unsigned* Xs = smem;
    unsigned* Ws = smem + 128 * 34;

    int a = blockIdx.y;
    int b0 = blockIdx.x * 128;
    int t = threadIdx.x;
    int wid = t >> 6, lane = t & 63, lm = lane & 15, lq = lane >> 4;
    int wrow = (wid & 1) * 64;
    int wcol = (wid >> 1) * 64;  // 0,64 -> sa; 128,192 -> se

    floatx4 acc[4][4];
#pragma unroll
    for (int mt = 0; mt < 4; ++mt)
#pragma unroll
        for (int nt = 0; nt < 4; ++nt)
#pragma unroll
            for (int e = 0; e < 4; ++e) acc[mt][nt][e] = 0.f;

    const unsigned* WtA = wt_l1 + (size_t)a * 24576;

    for (int c = 0; c < 3; ++c) {
        int kk = c * 64;
        __syncthreads();
        for (int idx = t; idx < 128 * 16; idx += 512) {
            int r = idx >> 4, c4 = idx & 15;
            int k = kk + c4 * 4;
            size_t grow = (size_t)a * B_N + b0g + b0 + r;
            float4 v;
            if (k < O_N) v = *(const float4*)&obs[grow * O_N + k];
            else if (k < IN_N) v = *(const float4*)&act[grow * ACT_N + (k - O_N)];
            else v = make_float4(0.f, 0.f, 0.f, 0.f);
            uint2* dst = (uint2*)&Xs[r * 34 + c4 * 2];
            *dst = make_uint2(pack_bf2(v.x, v.y), pack_bf2(v.z, v.w));
        }
        for (int idx = t; idx < 256 * 8; idx += 512) {
            int n = idx >> 3, c4 = idx & 7;
            uint4 w = *(const uint4*)&WtA[(size_t)n * 96 + (kk >> 1) + c4 * 4];
            uint2* dst = (uint2*)&Ws[n * 34 + c4 * 4];
            dst[0] = make_uint2(w.x, w.y);
            dst[1] = make_uint2(w.z, w.w);
        }
        __syncthreads();
#pragma unroll
        for (int s = 0; s < 2; ++s) {
            if (kk + s * 32 >= 160) break;
            short8 afr[4];
#pragma unroll
            for (int mt = 0; mt < 4; ++mt)
                afr[mt] = ld_frag(&Xs[(wrow + mt * 16 + lm) * 34 + s * 16 + lq * 4]);
#pragma unroll
            for (int nt = 0; nt < 4; ++nt) {
                short8 bfr = ld_frag(&Ws[(wcol + nt * 16 + lm) * 34 + s * 16 + lq * 4]);
#pragma unroll
                for (int mt = 0; mt < 4; ++mt)
                    acc[mt][nt] = __builtin_amdgcn_mfma_f32_16x16x32_bf16(
                        afr[mt], bfr, acc[mt][nt], 0, 0, 0);
            }
        }
    }

    int zsel = (wcol >= 128);
    unsigned short* outp = zsel ? se_us : sa_us;
    const float* bias = fb + zsel * 2048 + a * 128;
    int cbase = wcol & 127;
#pragma unroll
    for (int mt = 0; mt < 4; ++mt)
#pragma unroll
        for (int nt = 0; nt < 4; ++nt)
#pragma unroll
            for (int r = 0; r < 4; ++r) {
                int row = wrow + mt * 16 + lq * 4 + r;
                int col = cbase + nt * 16 + lm;
                float v = acc[mt][nt][r] + bias[col];
                v = v > 0.f ? v : 0.01f * v;
                outp[((size_t)(b0 + row) * 16 + a) * 128 + col] = f2bf(v);
            }
}

// ---- fused: NO input staging — A-frags direct from global (L3-hit). -----
// Phases: kv GEMM -> bar -> sel GEMM -> bar -> QK -> bar -> softmax/PV.
// 3 barriers (was 7); no Xs buffer fills; same MFMA count.
__global__ __launch_bounds__(256, 3) void k_fused(
    const unsigned* __restrict__ sa_u, const unsigned* __restrict__ se_u,
    const unsigned* __restrict__ wt_p1, const unsigned* __restrict__ wt_p2,
    const float* __restrict__ bv, unsigned short* __restrict__ other_us,
    int Bc) {
    __shared__ unsigned short keys_s[64 * 130];  // lg (f32) overlays after QK
    __shared__ unsigned short vals_s[64 * 136];
    __shared__ unsigned short sel_s[64 * 132];

    int bg0 = blockIdx.x * 4;
    int t = threadIdx.x;
    int wid = t >> 6, lane = t & 63, lm = lane & 15, lq = lane >> 4;

    const unsigned* sa_base = sa_u + (size_t)(bg0 * 16) * 64;
    const unsigned* se_base = se_u + (size_t)(bg0 * 16) * 64;

    // ---- merged keys|vals GEMM: N=256, wave = 64 rows x 64 cols ----
    {
        floatx4 acc[4][4];
#pragma unroll
        for (int mt = 0; mt < 4; ++mt)
#pragma unroll
            for (int nt = 0; nt < 4; ++nt)
#pragma unroll
                for (int e = 0; e < 4; ++e) acc[mt][nt][e] = 0.f;
#pragma unroll
        for (int s = 0; s < 4; ++s) {
            short8 afr[4];
#pragma unroll
            for (int mt = 0; mt < 4; ++mt)
                afr[mt] = ld_frag4(sa_base + (size_t)(mt * 16 + lm) * 64 + s * 16 + lq * 4);
#pragma unroll
            for (int nt = 0; nt < 4; ++nt) {
                int col = wid * 64 + nt * 16 + lm;  // 0..255 (keys|vals)
                short8 bfr = ld_frag4(wt_p1 + (size_t)col * 64 + s * 16 + lq * 4);
#pragma unroll
                for (int mt = 0; mt < 4; ++mt)
                    acc[mt][nt] = __builtin_amdgcn_mfma_f32_16x16x32_bf16(
                        afr[mt], bfr, acc[mt][nt], 0, 0, 0);
            }
        }
        if (wid < 2) {  // keys cols 0..127
#pragma unroll
            for (int mt = 0; mt < 4; ++mt)
#pragma unroll
                for (int nt = 0; nt < 4; ++nt)
#pragma unroll
                    for (int r = 0; r < 4; ++r) {
                        int row = mt * 16 + lq * 4 + r;
                        int col = wid * 64 + nt * 16 + lm;
                        keys_s[row * 130 + col] = f2bf(acc[mt][nt][r]);
                    }
        } else {  // vals cols 0..127 (+bias, lrelu)
#pragma unroll
            for (int mt = 0; mt < 4; ++mt)
#pragma unroll
                for (int nt = 0; nt < 4; ++nt) {
                    int col = (wid - 2) * 64 + nt * 16 + lm;
                    float bvc = bv[col];
#pragma unroll
                    for (int r = 0; r < 4; ++r) {
                        int row = mt * 16 + lq * 4 + r;
                        float v = acc[mt][nt][r] + bvc;
                        v = v > 0.f ? v : 0.01f * v;
                        vals_s[row * 136 + col] = f2bf(v);
                    }
                }
        }
    }
    __syncthreads();

    // ---- sel GEMM: wave = 64 rows x 32 cols, A-frags from global se ----
    {
        int wcol = wid * 32;
        floatx4 acc[4][2];
#pragma unroll
        for (int mt = 0; mt < 4; ++mt)
#pragma unroll
            for (int nt = 0; nt < 2; ++nt)
#pragma unroll
                for (int e = 0; e < 4; ++e) acc[mt][nt][e] = 0.f;
#pragma unroll
        for (int s = 0; s < 4; ++s) {
            short8 afr[4];
#pragma unroll
            for (int mt = 0; mt < 4; ++mt)
                afr[mt] = ld_frag4(se_base + (size_t)(mt * 16 + lm) * 64 + s * 16 + lq * 4);
#pragma unroll
            for (int nt = 0; nt < 2; ++nt) {
                int col = wcol + nt * 16 + lm;
                short8 bfr = ld_frag4(wt_p2 + (size_t)col * 64 + s * 16 + lq * 4);
#pragma unroll
                for (int mt = 0; mt < 4; ++mt)
                    acc[mt][nt] = __builtin_amdgcn_mfma_f32_16x16x32_bf16(
                        afr[mt], bfr, acc[mt][nt], 0, 0, 0);
            }
        }
#pragma unroll
        for (int mt = 0; mt < 4; ++mt)
#pragma unroll
            for (int nt = 0; nt < 2; ++nt)
#pragma unroll
                for (int r = 0; r < 4; ++r) {
                    int row = mt * 16 + lq * 4 + r;
                    int col = wcol + nt * 16 + lm;
                    sel_s[row * 132 + col] = f2bf(acc[mt][nt][r]);
                }
    }
    __syncthreads();

    // ---- QK^T via MFMA: wave wid = bsub; one mfma per head n ----
    const unsigned* selU = (const unsigned*)sel_s;
    const unsigned* keysU = (const unsigned*)keys_s;
    floatx4 lgacc[4];
#pragma unroll
    for (int n = 0; n < 4; ++n) {
        short8 af = ld_frag(&selU[(wid * 16 + lm) * 66 + n * 16 + lq * 4]);
        short8 bf = ld_frag(&keysU[(wid * 16 + lm) * 65 + n * 16 + lq * 4]);
        floatx4 z4 = {0.f, 0.f, 0.f, 0.f};
        lgacc[n] = __builtin_amdgcn_mfma_f32_16x16x32_bf16(af, bf, z4, 0, 0, 0);
    }
    __syncthreads();  // all QK reads complete before lg overlays keys

    // lg layout: [(bsub*4+n)*16 + i][16 j] fp32 (16 KB in keys region)
    float* lgs = (float*)keys_s;
#pragma unroll
    for (int n = 0; n < 4; ++n)
#pragma unroll
        for (int r = 0; r < 4; ++r) {
            int i = lq * 4 + r;
            lgs[((wid * 4 + n) * 16 + i) * 16 + lm] =
                lgacc[n][r] * 0.17677669529663687f;
        }
    asm volatile("" ::: "memory");  // wave-local: DS in-order; fence compiler

    int bsub = wid, n = (t >> 4) & 3, i = t & 15;
    float lg[16];
    {
        const float4* lgp = (const float4*)&lgs[((bsub * 4 + n) * 16 + i) * 16];
#pragma unroll
        for (int c = 0; c < 4; ++c) {
            float4 v = lgp[c];
            lg[4 * c] = v.x; lg[4 * c + 1] = v.y;
            lg[4 * c + 2] = v.z; lg[4 * c + 3] = v.w;
        }
    }
    lg[i] = NEGV;
    float m = lg[0];
#pragma unroll
    for (int j = 1; j < 16; ++j) m = fmaxf(m, lg[j]);
    float sum = 0.f;
#pragma unroll
    for (int j = 0; j < 16; ++j) { lg[j] = __expf(lg[j] - m); sum += lg[j]; }
    float inv = 1.f / sum;
#pragma unroll
    for (int j = 0; j < 16; ++j) lg[j] *= inv;

    // ---- PV: vals row for (agent j, bsub) = bsub*16 + j ----
    const unsigned* valsU = (const unsigned*)vals_s;
    float ov[32];
#pragma unroll
    for (int u = 0; u < 32; ++u) ov[u] = 0.f;
#pragma unroll
    for (int j = 0; j < 16; ++j) {
        const uint4* vrow = (const uint4*)&valsU[(bsub * 16 + j) * 68 + n * 16];
        float w = lg[j];
#pragma unroll
        for (int c = 0; c < 4; ++c) {
            uint4 x = vrow[c];
            ov[8 * c + 0] = fmaf(w, bflo(x.x), ov[8 * c + 0]);
            ov[8 * c + 1] = fmaf(w, bfhi(x.x), ov[8 * c + 1]);
            ov[8 * c + 2] = fmaf(w, bflo(x.y), ov[8 * c + 2]);
            ov[8 * c + 3] = fmaf(w, bfhi(x.y), ov[8 * c + 3]);
            ov[8 * c + 4] = fmaf(w, bflo(x.z), ov[8 * c + 4]);
            ov[8 * c + 5] = fmaf(w, bfhi(x.z), ov[8 * c + 5]);
            ov[8 * c + 6] = fmaf(w, bflo(x.w), ov[8 * c + 6]);
            ov[8 * c + 7] = fmaf(w, bfhi(x.w), ov[8 * c + 7]);
        }
    }
    {
        uint4* orow = (uint4*)&other_us[((size_t)(bg0 + bsub) * 16 + i) * 128 + n * 32];
#pragma unroll
        for (int h = 0; h < 2; ++h) {
            uint4 o;
            o.x = pack_bf2(ov[16 * h + 0], ov[16 * h + 1]);
            o.y = pack_bf2(ov[16 * h + 2], ov[16 * h + 3]);
            o.z = pack_bf2(ov[16 * h + 4], ov[16 * h + 5]);
            o.w = pack_bf2(ov[16 * h + 6], ov[16 * h + 7]);
            orow[2 * h] = o;
            o.x = pack_bf2(ov[16 * h + 8], ov[16 * h + 9]);
            o.y = pack_bf2(ov[16 * h + 10], ov[16 * h + 11]);
            o.z = pack_bf2(ov[16 * h + 12], ov[16 * h + 13]);
            o.w = pack_bf2(ov[16 * h + 14], ov[16 * h + 15]);
            orow[2 * h + 1] = o;
        }
    }
}

// ---- critic (R3-proven body): block 64x128, wave 32x64, acc[2][4] -------
__global__ __launch_bounds__(256, 4) void k_critic(
    const unsigned* __restrict__ se_u, const unsigned* __restrict__ other_u,
    const unsigned* __restrict__ wt_cr,
    const float* __restrict__ bc1, const float* __restrict__ actions,
    const float* __restrict__ wt_c2, const float* __restrict__ bc2,
    float* __restrict__ qout, int b0g, int Bc) {
    __shared__ unsigned smem[(64 + 128) * 34];
    unsigned* Xs = smem;
    unsigned* Ws = smem + 64 * 34;

    int a = blockIdx.y;
    int b0 = blockIdx.x * 64;
    int t = threadIdx.x;
    int wid = t >> 6, lane = t & 63, lm = lane & 15, lq = lane >> 4;
    int wrow = (wid & 1) * 32;
    int wcol = (wid >> 1) * 64;

    floatx4 acc[2][4];
#pragma unroll
    for (int mt = 0; mt < 2; ++mt)
#pragma unroll
        for (int nt = 0; nt < 4; ++nt)
#pragma unroll
            for (int e = 0; e < 4; ++e) acc[mt][nt][e] = 0.f;

    const unsigned* WtA = wt_cr + (size_t)a * 16384;

    for (int c = 0; c < 4; ++c) {
        int kk = c * 64;
        __syncthreads();
        const unsigned* src = (c < 2) ? se_u : other_u;
        int off = (c & 1) * 32;
        for (int idx = t; idx < 64 * 8; idx += 256) {
            int r = idx >> 3, c4 = idx & 7;
            uint4 v = *(const uint4*)&src[((size_t)(b0 + r) * 16 + a) * 64 + off + c4 * 4];
            uint2* dst = (uint2*)&Xs[r * 34 + c4 * 4];
            dst[0] = make_uint2(v.x, v.y);
            dst[1] = make_uint2(v.z, v.w);
        }
        for (int idx = t; idx < 128 * 8; idx += 256) {
            int n = idx >> 3, c4 = idx & 7;
            uint4 w = *(const uint4*)&WtA[(size_t)n * 128 + (kk >> 1) + c4 * 4];
            uint2* dst = (uint2*)&Ws[n * 34 + c4 * 4];
            dst[0] = make_uint2(w.x, w.y);
            dst[1] = make_uint2(w.z, w.w);
        }
        __syncthreads();
#pragma unroll
        for (int s = 0; s < 2; ++s) {
            short8 afr[2];
#pragma unroll
            for (int mt = 0; mt < 2; ++mt)
                afr[mt] = ld_frag(&Xs[(wrow + mt * 16 + lm) * 34 + s * 16 + lq * 4]);
#pragma unroll
            for (int nt = 0; nt < 4; ++nt) {
                short8 bfr = ld_frag(&Ws[(wcol + nt * 16 + lm) * 34 + s * 16 + lq * 4]);
#pragma unroll
                for (int mt = 0; mt < 2; ++mt)
                    acc[mt][nt] = __builtin_amdgcn_mfma_f32_16x16x32_bf16(
                        afr[mt], bfr, acc[mt][nt], 0, 0, 0);
            }
        }
    }

    __syncthreads();
    unsigned short* hbuf = (unsigned short*)smem;  // [64][132]
#pragma unroll
    for (int mt = 0; mt < 2; ++mt)
#pragma unroll
        for (int nt = 0; nt < 4; ++nt)
#pragma unroll
            for (int r = 0; r < 4; ++r) {
                int row = wrow + mt * 16 + lq * 4 + r;
                int col = wcol + nt * 16 + lm;
                float v = acc[mt][nt][r] + bc1[a * H_N + col];
                v = v > 0.f ? v : 0.01f * v;
                hbuf[row * 132 + col] = f2bf(v);
            }
    __syncthreads();
    if (t < 64) {
        size_t arow = (size_t)a * B_N + b0g + b0 + t;
        const float* ap = &actions[arow * ACT_N];
        float bestv = ap[0];
        int bi = 0;
        for (int o = 1; o < ACT_N; ++o) {
            float v = ap[o];
            if (v > bestv) { bestv = v; bi = o; }
        }
        float q = bc2[a * ACT_N + bi];
        const float4* w4p = (const float4*)&wt_c2[((size_t)a * ACT_N + bi) * H_N];
        const uint2* hp2 = (const uint2*)&hbuf[t * 132];
#pragma unroll
        for (int h4 = 0; h4 < 32; ++h4) {
            float4 w4 = w4p[h4];
            uint2 hh = hp2[h4];
            q = fmaf(bflo(hh.x), w4.x, q);
            q = fmaf(bfhi(hh.x), w4.y, q);
            q = fmaf(bflo(hh.y), w4.z, q);
            q = fmaf(bfhi(hh.y), w4.w, q);
        }
        qout[arow] = q;
    }
}

extern "C" void kernel_launch(void* const* d_in, const int* in_sizes, int n_in,
                              void* d_out, int out_size, void* d_ws, size_t ws_size,
                              hipStream_t stream) {
    const float* obs     = (const float*)d_in[0];
    const float* actions = (const float*)d_in[1];
    const float* W_sa    = (const float*)d_in[2];
    const float* b_sa    = (const float*)d_in[3];
    const float* W_s     = (const float*)d_in[4];
    const float* b_s     = (const float*)d_in[5];
    const float* Wk      = (const float*)d_in[6];
    const float* Wsel    = (const float*)d_in[7];
    const float* Wv      = (const float*)d_in[8];
    const float* bv      = (const float*)d_in[9];
    const float* Wc1     = (const float*)d_in[10];
    const float* bc1     = (const float*)d_in[11];
    const float* Wc2     = (const float*)d_in[12];
    const float* bc2     = (const float*)d_in[13];
    float* out = (float*)d_out;
    char* ws = (char*)d_ws;

    size_t o = 0;
    float* gsum = (float*)(ws + o); o += 2304 * 4;
    float* gsq  = (float*)(ws + o); o += 2304 * 4;
    unsigned* wt_l1 = (unsigned*)(ws + o); o += (size_t)393216 * 4;
    unsigned* wt_p1 = (unsigned*)(ws + o); o += (size_t)16384 * 4;
    unsigned* wt_p2 = (unsigned*)(ws + o); o += (size_t)8192 * 4;
    unsigned* wt_cr = (unsigned*)(ws + o); o += (size_t)262144 * 4;
    float* fb = (float*)(ws + o); o += (size_t)4096 * 4;
    float* wt_c2 = (float*)(ws + o); o += (size_t)32768 * 4;
    size_t fixed = o;

    int Bc = B_N;
    while (Bc > 128 && fixed + 12288ull * Bc > ws_size) Bc >>= 1;

    unsigned short* sa_us = (unsigned short*)(ws + o); o += (size_t)A_N * Bc * 128 * 2;
    unsigned short* se_us = (unsigned short*)(ws + o); o += (size_t)A_N * Bc * 128 * 2;
    unsigned short* ot_us = (unsigned short*)(ws + o); o += (size_t)A_N * Bc * 128 * 2;

    k_zero<<<dim3(18), 256, 0, stream>>>(gsum, 2 * A_N * IN_N);
    k_stats<<<dim3(A_N * 16), 256, 0, stream>>>(obs, actions, gsum, gsq);
    k_finalize<<<dim3(9), 256, 0, stream>>>(gsum, gsq);
    k_wprep<<<dim3(C2E / 256), 256, 0, stream>>>(W_sa, W_s, Wk, Wsel, Wv, Wc1, Wc2,
                                                 gsq, wt_l1, wt_p1, wt_p2, wt_cr, wt_c2);
    k_bfold<<<dim3(A_N), 256, 0, stream>>>(gsum, gsq, W_sa, W_s, b_sa, b_s, fb);

    for (int b0g = 0; b0g < B_N; b0g += Bc) {
        k_l1<<<dim3(Bc / 128, A_N), 512, 0, stream>>>(
            obs, actions, wt_l1, fb, sa_us, se_us, b0g, Bc);
        k_fused<<<dim3(Bc / 4), 256, 0, stream>>>(
            (const unsigned*)sa_us, (const unsigned*)se_us, wt_p1, wt_p2, bv,
            ot_us, Bc);
        k_critic<<<dim3(Bc / 64, A_N), 256, 0, stream>>>(
            (const unsigned*)se_us, (const unsigned*)ot_us, wt_cr, bc1,
            actions, wt_c2, bc2, out, b0g, Bc);
    }
}

// Round 6
// 266.592 us; speedup vs baseline: 1.2636x; 1.1232x over previous
//
#include <hip/hip_runtime.h>
#include <hip/hip_bf16.h>

#define A_N 16
#define B_N 8192
#define O_N 128
#define ACT_N 16
#define H_N 128
#define NH_N 4
#define D_N 32
#define IN_N 144
#define NEGV -1e9f

typedef __attribute__((ext_vector_type(8))) short short8;
typedef __attribute__((ext_vector_type(4))) float floatx4;

// ---- bf16 helpers (RNE) -------------------------------------------------
static __device__ inline unsigned short f2bf(float f) {
    union { float f; unsigned u; } x{f};
    unsigned u = x.u + 0x7FFFu + ((x.u >> 16) & 1u);
    return (unsigned short)(u >> 16);
}
static __device__ inline unsigned pack_bf2(float a, float b) {
    union { float f; unsigned u; } xa{a}, xb{b};
    unsigned ua = xa.u + 0x7FFFu + ((xa.u >> 16) & 1u);
    unsigned ub = xb.u + 0x7FFFu + ((xb.u >> 16) & 1u);
    return (ua >> 16) | (ub & 0xFFFF0000u);
}
static __device__ inline float bf2f(unsigned short h) {
    union { unsigned u; float f; } x;
    x.u = ((unsigned)h) << 16;
    return x.f;
}
static __device__ inline float bflo(unsigned u) {
    union { unsigned u; float f; } x; x.u = u << 16; return x.f;
}
static __device__ inline float bfhi(unsigned u) {
    union { unsigned u; float f; } x; x.u = u & 0xFFFF0000u; return x.f;
}
static __device__ inline short8 ld_frag(const unsigned* p) {
    union { unsigned u[4]; short8 v; } x;
    uint2 lo = *(const uint2*)p;
    uint2 hi = *(const uint2*)(p + 2);
    x.u[0] = lo.x; x.u[1] = lo.y; x.u[2] = hi.x; x.u[3] = hi.y;
    return x.v;
}
static __device__ inline short8 ld_frag4(const unsigned* p) {
    union { uint4 q; short8 v; } x;
    x.q = *(const uint4*)p;
    return x.v;
}

// ---- stats: per-slab partials, NO global atomics, no zero pass ----------
__global__ __launch_bounds__(256) void k_stats(const float* __restrict__ obs,
                                               const float* __restrict__ act,
                                               float* __restrict__ gsumP,
                                               float* __restrict__ gsqP) {
    __shared__ float ssum[IN_N];
    __shared__ float ssq[IN_N];
    int a = blockIdx.x >> 4;
    int slab = blockIdx.x & 15;
    int r0 = slab * 512;
    int t = threadIdx.x;
    if (t < IN_N) { ssum[t] = 0.f; ssq[t] = 0.f; }
    __syncthreads();
    {
        int c0 = (t & 31) * 4, rg = t >> 5;  // 8 row-groups x 32 col-quads
        const float* p = obs + ((size_t)a * B_N + r0 + rg) * O_N + c0;
        float s0 = 0.f, s1 = 0.f, s2 = 0.f, s3 = 0.f;
        float q0 = 0.f, q1 = 0.f, q2 = 0.f, q3 = 0.f;
#pragma unroll 4
        for (int i = 0; i < 64; ++i) {
            float4 v = *(const float4*)(p + (size_t)i * 8 * O_N);
            s0 += v.x; q0 += v.x * v.x;
            s1 += v.y; q1 += v.y * v.y;
            s2 += v.z; q2 += v.z * v.z;
            s3 += v.w; q3 += v.w * v.w;
        }
        atomicAdd(&ssum[c0 + 0], s0); atomicAdd(&ssq[c0 + 0], q0);
        atomicAdd(&ssum[c0 + 1], s1); atomicAdd(&ssq[c0 + 1], q1);
        atomicAdd(&ssum[c0 + 2], s2); atomicAdd(&ssq[c0 + 2], q2);
        atomicAdd(&ssum[c0 + 3], s3); atomicAdd(&ssq[c0 + 3], q3);
    }
    if (t < 128) {
        int f = t & 15, rg = t >> 4;  // 8 row-groups x 16 features
        const float* p = act + ((size_t)a * B_N + r0 + rg) * ACT_N + f;
        float s = 0.f, q = 0.f;
#pragma unroll 4
        for (int i = 0; i < 64; ++i) {
            float v = p[(size_t)i * 8 * ACT_N];
            s += v; q += v * v;
        }
        atomicAdd(&ssum[O_N + f], s);
        atomicAdd(&ssq[O_N + f], q);
    }
    __syncthreads();
    if (t < IN_N) {
        gsumP[(a * 16 + slab) * IN_N + t] = ssum[t];
        gsqP[(a * 16 + slab) * IN_N + t] = ssq[t];
    }
}

__global__ __launch_bounds__(256) void k_finalize(const float* __restrict__ gsumP,
                                                  const float* __restrict__ gsqP,
                                                  float* __restrict__ mean,
                                                  float* __restrict__ rstd) {
    int i = blockIdx.x * 256 + threadIdx.x;
    if (i < A_N * IN_N) {
        int a = i / IN_N, f = i - a * IN_N;
        float s = 0.f, q = 0.f;
#pragma unroll
        for (int sl = 0; sl < 16; ++sl) {
            s += gsumP[(a * 16 + sl) * IN_N + f];
            q += gsqP[(a * 16 + sl) * IN_N + f];
        }
        const float invB = 1.f / (float)B_N;
        float m = s * invB;
        float v = fmaxf(q * invB - m * m, 0.f);
        mean[i] = m;
        rstd[i] = rsqrtf(v + 1e-5f);
    }
}

// ---- weight prep + folded biases (bfold merged as tail range) -----------
#define L1E 393216
#define P1E 409600
#define P2E 417792
#define CRE 679936
#define C2E 712704
#define BFE (C2E + 4096)
__global__ __launch_bounds__(256) void k_wprep(
    const float* __restrict__ W_sa, const float* __restrict__ W_s,
    const float* __restrict__ Wk, const float* __restrict__ Wsel,
    const float* __restrict__ Wv, const float* __restrict__ Wc1,
    const float* __restrict__ Wc2, const float* __restrict__ mean,
    const float* __restrict__ rstd,
    const float* __restrict__ b_sa, const float* __restrict__ b_s,
    unsigned* __restrict__ wt_l1, unsigned* __restrict__ wt_p1,
    unsigned* __restrict__ wt_p2, unsigned* __restrict__ wt_cr,
    float* __restrict__ wt_c2, float* __restrict__ fb) {
    int idx = blockIdx.x * 256 + threadIdx.x;
    if (idx < L1E) {
        int a = idx / 24576, rem = idx % 24576;
        int n = rem & 255, kp = rem >> 8;  // kp 0..95
        int k0 = 2 * kp, k1 = k0 + 1;
        float v0 = 0.f, v1 = 0.f;
        if (n < 128) {
            if (k0 < IN_N) v0 = W_sa[((size_t)a * IN_N + k0) * H_N + n] * rstd[a * IN_N + k0];
            if (k1 < IN_N) v1 = W_sa[((size_t)a * IN_N + k1) * H_N + n] * rstd[a * IN_N + k1];
        } else {
            int m = n - 128;
            if (k0 < O_N) v0 = W_s[((size_t)a * O_N + k0) * H_N + m] * rstd[a * IN_N + k0];
            if (k1 < O_N) v1 = W_s[((size_t)a * O_N + k1) * H_N + m] * rstd[a * IN_N + k1];
        }
        wt_l1[(size_t)a * 24576 + n * 96 + kp] = pack_bf2(v0, v1);
    } else if (idx < P1E) {
        int i2 = idx - L1E;
        int n = i2 & 255, kp = i2 >> 8;
        int k0 = 2 * kp;
        float v0, v1;
        if (n < 128) {
            const float* w = Wk + ((size_t)(n >> 5) * H_N) * D_N + (n & 31);
            v0 = w[(size_t)k0 * D_N]; v1 = w[(size_t)(k0 + 1) * D_N];
        } else {
            int m = n - 128;
            const float* w = Wv + ((size_t)(m >> 5) * H_N) * D_N + (m & 31);
            v0 = w[(size_t)k0 * D_N]; v1 = w[(size_t)(k0 + 1) * D_N];
        }
        wt_p1[n * 64 + kp] = pack_bf2(v0, v1);
    } else if (idx < P2E) {
        int i3 = idx - P1E;
        int n = i3 & 127, kp = i3 >> 7;
        int k0 = 2 * kp;
        const float* w = Wsel + ((size_t)(n >> 5) * H_N) * D_N + (n & 31);
        wt_p2[n * 64 + kp] = pack_bf2(w[(size_t)k0 * D_N], w[(size_t)(k0 + 1) * D_N]);
    } else if (idx < CRE) {
        int i4 = idx - P2E;
        int a = i4 >> 14, r = i4 & 16383;
        int n = r & 127, kp = r >> 7;
        int k0 = 2 * kp;
        const float* w = Wc1 + (size_t)a * 256 * H_N + n;
        wt_cr[(size_t)a * 16384 + n * 128 + kp] =
            pack_bf2(w[(size_t)k0 * H_N], w[(size_t)(k0 + 1) * H_N]);
    } else if (idx < C2E) {
        int i5 = idx - CRE;
        int a = i5 >> 11, rem = i5 & 2047;
        int oo = rem >> 7, h = rem & 127;
        wt_c2[i5] = Wc2[((size_t)a * H_N + h) * ACT_N + oo];
    } else if (idx < BFE) {
        int i6 = idx - C2E;
        int a = i6 >> 8, c = i6 & 255;
        float s = 0.f;
        if (c < 128) {
            for (int k = 0; k < IN_N; ++k)
                s += mean[a * IN_N + k] * rstd[a * IN_N + k] *
                     W_sa[((size_t)a * IN_N + k) * H_N + c];
            fb[a * 128 + c] = b_sa[a * H_N + c] - s;
        } else {
            int m = c - 128;
            for (int k = 0; k < O_N; ++k)
                s += mean[a * IN_N + k] * rstd[a * IN_N + k] *
                     W_s[((size_t)a * O_N + k) * H_N + m];
            fb[2048 + a * 128 + m] = b_s[a * H_N + m] - s;
        }
    }
}

// ---- L1 merged (R3-proven body): one block does sa AND se. --------------
__global__ __launch_bounds__(512, 2) void k_l1(
    const float* __restrict__ obs, const float* __restrict__ act,
    const unsigned* __restrict__ wt_l1, const float* __restrict__ fb,
    unsigned short* __restrict__ sa_us, unsigned short* __restrict__ se_us,
    int b0g, int Bc) {
    __shared__ unsigned smem[(128 + 256) * 34];
    unsigned* Xs = smem;
    unsigned* Ws = smem + 128 * 34;

    int a = blockIdx.y;
    int b0 = blockIdx.x * 128;
    int t = threadIdx.x;
    int wid = t >> 6, lane = t & 63, lm = lane & 15, lq = lane >> 4;
    int wrow = (wid & 1) * 64;
    int wcol = (wid >> 1) * 64;  // 0,64 -> sa; 128,192 -> se

    floatx4 acc[4][4];
#pragma unroll
    for (int mt = 0; mt < 4; ++mt)
#pragma unroll
        for (int nt = 0; nt < 4; ++nt)
#pragma unroll
            for (int e = 0; e < 4; ++e) acc[mt][nt][e] = 0.f;

    const unsigned* WtA = wt_l1 + (size_t)a * 24576;

    for (int c = 0; c < 3; ++c) {
        int kk = c * 64;
        __syncthreads();
        for (int idx = t; idx < 128 * 16; idx += 512) {
            int r = idx >> 4, c4 = idx & 15;
            int k = kk + c4 * 4;
            size_t grow = (size_t)a * B_N + b0g + b0 + r;
            float4 v;
            if (k < O_N) v = *(const float4*)&obs[grow * O_N + k];
            else if (k < IN_N) v = *(const float4*)&act[grow * ACT_N + (k - O_N)];
            else v = make_float4(0.f, 0.f, 0.f, 0.f);
            uint2* dst = (uint2*)&Xs[r * 34 + c4 * 2];
            *dst = make_uint2(pack_bf2(v.x, v.y), pack_bf2(v.z, v.w));
        }
        for (int idx = t; idx < 256 * 8; idx += 512) {
            int n = idx >> 3, c4 = idx & 7;
            uint4 w = *(const uint4*)&WtA[(size_t)n * 96 + (kk >> 1) + c4 * 4];
            uint2* dst = (uint2*)&Ws[n * 34 + c4 * 4];
            dst[0] = make_uint2(w.x, w.y);
            dst[1] = make_uint2(w.z, w.w);
        }
        __syncthreads();
#pragma unroll
        for (int s = 0; s < 2; ++s) {
            if (kk + s * 32 >= 160) break;
            short8 afr[4];
#pragma unroll
            for (int mt = 0; mt < 4; ++mt)
                afr[mt] = ld_frag(&Xs[(wrow + mt * 16 + lm) * 34 + s * 16 + lq * 4]);
#pragma unroll
            for (int nt = 0; nt < 4; ++nt) {
                short8 bfr = ld_frag(&Ws[(wcol + nt * 16 + lm) * 34 + s * 16 + lq * 4]);
#pragma unroll
                for (int mt = 0; mt < 4; ++mt)
                    acc[mt][nt] = __builtin_amdgcn_mfma_f32_16x16x32_bf16(
                        afr[mt], bfr, acc[mt][nt], 0, 0, 0);
            }
        }
    }

    int zsel = (wcol >= 128);
    unsigned short* outp = zsel ? se_us : sa_us;
    const float* bias = fb + zsel * 2048 + a * 128;
    int cbase = wcol & 127;
#pragma unroll
    for (int mt = 0; mt < 4; ++mt)
#pragma unroll
        for (int nt = 0; nt < 4; ++nt)
#pragma unroll
            for (int r = 0; r < 4; ++r) {
                int row = wrow + mt * 16 + lq * 4 + r;
                int col = cbase + nt * 16 + lm;
                float v = acc[mt][nt][r] + bias[col];
                v = v > 0.f ? v : 0.01f * v;
                outp[((size_t)(b0 + row) * 16 + a) * 128 + col] = f2bf(v);
            }
}

// ---- fused (R4 staging structure + MFMA-PV tail) ------------------------
// kv GEMM (keys -> keys_s, vals -> TRANSPOSED valsT[bsub][d][j]);
// sel GEMM; QK^T swapped (D[j][i] -> softmax lane-local via shfl_xor);
// P packed bf16 -> PV B-frag via 4 bpermutes; PV = 8 MFMAs. No logit LDS,
// no post-QK barrier, scalar PV eliminated.
__global__ __launch_bounds__(256, 3) void k_fused(
    const unsigned* __restrict__ sa_u, const unsigned* __restrict__ se_u,
    const unsigned* __restrict__ wt_p1, const unsigned* __restrict__ wt_p2,
    const float* __restrict__ bv, unsigned short* __restrict__ other_us,
    int Bc) {
    __shared__ unsigned Xs[64 * 66];              // 16896 B (sa/se, then sel)
    __shared__ unsigned short keys_s[64 * 130];   // 16640 B
    __shared__ unsigned short valsT[4 * 128 * 16];// 16384 B [bsub][d][j]
    unsigned short* sel_s = (unsigned short*)Xs;

    int bg0 = blockIdx.x * 4;
    int t = threadIdx.x;
    int wid = t >> 6, lane = t & 63, lm = lane & 15, lq = lane >> 4;

    const unsigned* sa_base = sa_u + (size_t)(bg0 * 16) * 64;
    const unsigned* se_base = se_u + (size_t)(bg0 * 16) * 64;

    // ---- stage sa: 64 contiguous rows, linear uint4 stream ----
    for (int idx = t; idx < 64 * 16; idx += 256) {
        int r = idx >> 4, c4 = idx & 15;
        uint4 v = *(const uint4*)&sa_base[(size_t)idx * 4];
        uint2* dst = (uint2*)&Xs[r * 66 + c4 * 4];
        dst[0] = make_uint2(v.x, v.y);
        dst[1] = make_uint2(v.z, v.w);
    }
    // ---- issue se loads NOW; land after kv phase (T14) ----
    uint4 seR[4];
#pragma unroll
    for (int ii = 0; ii < 4; ++ii)
        seR[ii] = *(const uint4*)&se_base[(size_t)(t + ii * 256) * 4];
    __syncthreads();

    // ---- merged keys|vals GEMM: N=256, wave = 64 rows x 64 cols ----
    {
        floatx4 acc[4][4];
#pragma unroll
        for (int mt = 0; mt < 4; ++mt)
#pragma unroll
            for (int nt = 0; nt < 4; ++nt)
#pragma unroll
                for (int e = 0; e < 4; ++e) acc[mt][nt][e] = 0.f;
#pragma unroll
        for (int s = 0; s < 4; ++s) {
            short8 afr[4];
#pragma unroll
            for (int mt = 0; mt < 4; ++mt)
                afr[mt] = ld_frag(&Xs[(mt * 16 + lm) * 66 + s * 16 + lq * 4]);
#pragma unroll
            for (int nt = 0; nt < 4; ++nt) {
                int col = wid * 64 + nt * 16 + lm;  // 0..255 (keys|vals)
                short8 bfr = ld_frag4(wt_p1 + (size_t)col * 64 + s * 16 + lq * 4);
#pragma unroll
                for (int mt = 0; mt < 4; ++mt)
                    acc[mt][nt] = __builtin_amdgcn_mfma_f32_16x16x32_bf16(
                        afr[mt], bfr, acc[mt][nt], 0, 0, 0);
            }
        }
        if (wid < 2) {  // keys cols 0..127 -> keys_s[row][col]
#pragma unroll
            for (int mt = 0; mt < 4; ++mt)
#pragma unroll
                for (int nt = 0; nt < 4; ++nt)
#pragma unroll
                    for (int r = 0; r < 4; ++r) {
                        int row = mt * 16 + lq * 4 + r;
                        int col = wid * 64 + nt * 16 + lm;
                        keys_s[row * 130 + col] = f2bf(acc[mt][nt][r]);
                    }
        } else {  // vals -> valsT[bsub=mt][d][j]; j = lq*4+r packed as uint2
#pragma unroll
            for (int mt = 0; mt < 4; ++mt)
#pragma unroll
                for (int nt = 0; nt < 4; ++nt) {
                    int d = (wid - 2) * 64 + nt * 16 + lm;
                    float bvc = bv[d];
                    float v0 = acc[mt][nt][0] + bvc; v0 = v0 > 0.f ? v0 : 0.01f * v0;
                    float v1 = acc[mt][nt][1] + bvc; v1 = v1 > 0.f ? v1 : 0.01f * v1;
                    float v2 = acc[mt][nt][2] + bvc; v2 = v2 > 0.f ? v2 : 0.01f * v2;
                    float v3 = acc[mt][nt][3] + bvc; v3 = v3 > 0.f ? v3 : 0.01f * v3;
                    uint2 o = make_uint2(pack_bf2(v0, v1), pack_bf2(v2, v3));
                    *(uint2*)&valsT[mt * 2048 + d * 16 + lq * 4] = o;
                }
        }
    }
    __syncthreads();

    // ---- write prefetched se rows (overwrite sa) ----
#pragma unroll
    for (int ii = 0; ii < 4; ++ii) {
        int idx = t + ii * 256;
        int r = idx >> 4, c4 = idx & 15;
        uint2* dst = (uint2*)&Xs[r * 66 + c4 * 4];
        dst[0] = make_uint2(seR[ii].x, seR[ii].y);
        dst[1] = make_uint2(seR[ii].z, seR[ii].w);
    }
    __syncthreads();

    // ---- sel GEMM: wave = 64 rows x 32 cols ----
    {
        int wcol = wid * 32;
        floatx4 acc[4][2];
#pragma unroll
        for (int mt = 0; mt < 4; ++mt)
#pragma unroll
            for (int nt = 0; nt < 2; ++nt)
#pragma unroll
                for (int e = 0; e < 4; ++e) acc[mt][nt][e] = 0.f;
#pragma unroll
        for (int s = 0; s < 4; ++s) {
            short8 afr[4];
#pragma unroll
            for (int mt = 0; mt < 4; ++mt)
                afr[mt] = ld_frag(&Xs[(mt * 16 + lm) * 66 + s * 16 + lq * 4]);
#pragma unroll
            for (int nt = 0; nt < 2; ++nt) {
                int col = wcol + nt * 16 + lm;
                short8 bfr = ld_frag4(wt_p2 + (size_t)col * 64 + s * 16 + lq * 4);
#pragma unroll
                for (int mt = 0; mt < 4; ++mt)
                    acc[mt][nt] = __builtin_amdgcn_mfma_f32_16x16x32_bf16(
                        afr[mt], bfr, acc[mt][nt], 0, 0, 0);
            }
        }
        __syncthreads();  // all waves done reading Xs(se)
#pragma unroll
        for (int mt = 0; mt < 4; ++mt)
#pragma unroll
            for (int nt = 0; nt < 2; ++nt)
#pragma unroll
                for (int r = 0; r < 4; ++r) {
                    int row = mt * 16 + lq * 4 + r;
                    int col = wcol + nt * 16 + lm;
                    sel_s[row * 132 + col] = f2bf(acc[mt][nt][r]);
                }
    }
    __syncthreads();

    // ---- QK^T SWAPPED: D[j][i] per head; lane: i = lm, j = lq*4+r ----
    const unsigned* selU = (const unsigned*)sel_s;
    const unsigned* keysU = (const unsigned*)keys_s;
    int bsub = wid;
    floatx4 lgacc[4];
#pragma unroll
    for (int n = 0; n < 4; ++n) {
        short8 af = ld_frag(&keysU[(bsub * 16 + lm) * 65 + n * 16 + lq * 4]);  // keys (A rows=j)
        short8 bf = ld_frag(&selU[(bsub * 16 + lm) * 66 + n * 16 + lq * 4]);   // sel  (B rows=i)
        floatx4 z4 = {0.f, 0.f, 0.f, 0.f};
        lgacc[n] = __builtin_amdgcn_mfma_f32_16x16x32_bf16(af, bf, z4, 0, 0, 0);
    }

    // ---- softmax over j, lane-local + shfl_xor(16/32); pack P to bf16 ----
    const float scale = 0.17677669529663687f;
    int dr = lm - lq * 4;  // j == i  <=>  dr == r
    unsigned pq0[4], pq1[4];
#pragma unroll
    for (int n = 0; n < 4; ++n) {
        float p0 = lgacc[n][0] * scale;
        float p1 = lgacc[n][1] * scale;
        float p2 = lgacc[n][2] * scale;
        float p3 = lgacc[n][3] * scale;
        if (dr == 0) p0 = NEGV;
        if (dr == 1) p1 = NEGV;
        if (dr == 2) p2 = NEGV;
        if (dr == 3) p3 = NEGV;
        float m = fmaxf(fmaxf(p0, p1), fmaxf(p2, p3));
        m = fmaxf(m, __shfl_xor(m, 16));
        m = fmaxf(m, __shfl_xor(m, 32));
        p0 = __expf(p0 - m); p1 = __expf(p1 - m);
        p2 = __expf(p2 - m); p3 = __expf(p3 - m);
        float s = p0 + p1 + p2 + p3;
        s += __shfl_xor(s, 16);
        s += __shfl_xor(s, 32);
        float inv = 1.f / s;
        pq0[n] = pack_bf2(p0 * inv, p1 * inv);  // j = lq*4+0, +1
        pq1[n] = pack_bf2(p2 * inv, p3 * inv);  // j = lq*4+2, +3
    }

    // ---- PV via MFMA: out[d][i] = sum_j valsT[d][j] * P[j][i] ----
    // B-frag (P): lane needs j = 8g+0..7 for g=lq&1 (lq>=2 -> zero pad of K=32)
    const unsigned* valsTU = (const unsigned*)valsT;
    int g = lq & 1;
    int s0l = (g << 5) + lm;       // lane holding j = 8g+0..3
    int s1l = s0l + 16;            // lane holding j = 8g+4..7
    size_t obase = ((size_t)(bg0 + bsub) * 16 + lm) * 128;
#pragma unroll
    for (int n = 0; n < 4; ++n) {
        unsigned b0 = __shfl(pq0[n], s0l);
        unsigned b1 = __shfl(pq1[n], s0l);
        unsigned b2 = __shfl(pq0[n], s1l);
        unsigned b3 = __shfl(pq1[n], s1l);
        if (lq >= 2) { b0 = 0u; b1 = 0u; b2 = 0u; b3 = 0u; }
        short8 bfr;
        {
            union { unsigned u[4]; short8 v; } x;
            x.u[0] = b0; x.u[1] = b1; x.u[2] = b2; x.u[3] = b3;
            bfr = x.v;
        }
#pragma unroll
        for (int dt = 0; dt < 2; ++dt) {
            int d = n * 32 + dt * 16 + lm;
            uint4 av = *(const uint4*)(valsTU + ((bsub << 10) + d * 8 + (g << 2)));
            if (lq >= 2) { av.x = 0u; av.y = 0u; av.z = 0u; av.w = 0u; }
            short8 afr;
            { union { uint4 q; short8 v; } x; x.q = av; afr = x.v; }
            floatx4 z4 = {0.f, 0.f, 0.f, 0.f};
            floatx4 c = __builtin_amdgcn_mfma_f32_16x16x32_bf16(afr, bfr, z4, 0, 0, 0);
            uint2 o = make_uint2(pack_bf2(c[0], c[1]), pack_bf2(c[2], c[3]));
            *(uint2*)&other_us[obase + n * 32 + dt * 16 + lq * 4] = o;
        }
    }
}

// ---- critic (R3-proven body): block 64x128, wave 32x64, acc[2][4] -------
__global__ __launch_bounds__(256, 4) void k_critic(
    const unsigned* __restrict__ se_u, const unsigned* __restrict__ other_u,
    const unsigned* __restrict__ wt_cr,
    const float* __restrict__ bc1, const float* __restrict__ actions,
    const float* __restrict__ wt_c2, const float* __restrict__ bc2,
    float* __restrict__ qout, int b0g, int Bc) {
    __shared__ unsigned smem[(64 + 128) * 34];
    unsigned* Xs = smem;
    unsigned* Ws = smem + 64 * 34;

    int a = blockIdx.y;
    int b0 = blockIdx.x * 64;
    int t = threadIdx.x;
    int wid = t >> 6, lane = t & 63, lm = lane & 15, lq = lane >> 4;
    int wrow = (wid & 1) * 32;
    int wcol = (wid >> 1) * 64;

    floatx4 acc[2][4];
#pragma unroll
    for (int mt = 0; mt < 2; ++mt)
#pragma unroll
        for (int nt = 0; nt < 4; ++nt)
#pragma unroll
            for (int e = 0; e < 4; ++e) acc[mt][nt][e] = 0.f;

    const unsigned* WtA = wt_cr + (size_t)a * 16384;

    for (int c = 0; c < 4; ++c) {
        int kk = c * 64;
        __syncthreads();
        const unsigned* src = (c < 2) ? se_u : other_u;
        int off = (c & 1) * 32;
        for (int idx = t; idx < 64 * 8; idx += 256) {
            int r = idx >> 3, c4 = idx & 7;
            uint4 v = *(const uint4*)&src[((size_t)(b0 + r) * 16 + a) * 64 + off + c4 * 4];
            uint2* dst = (uint2*)&Xs[r * 34 + c4 * 4];
            dst[0] = make_uint2(v.x, v.y);
            dst[1] = make_uint2(v.z, v.w);
        }
        for (int idx = t; idx < 128 * 8; idx += 256) {
            int n = idx >> 3, c4 = idx & 7;
            uint4 w = *(const uint4*)&WtA[(size_t)n * 128 + (kk >> 1) + c4 * 4];
            uint2* dst = (uint2*)&Ws[n * 34 + c4 * 4];
            dst[0] = make_uint2(w.x, w.y);
            dst[1] = make_uint2(w.z, w.w);
        }
        __syncthreads();
#pragma unroll
        for (int s = 0; s < 2; ++s) {
            short8 afr[2];
#pragma unroll
            for (int mt = 0; mt < 2; ++mt)
                afr[mt] = ld_frag(&Xs[(wrow + mt * 16 + lm) * 34 + s * 16 + lq * 4]);
#pragma unroll
            for (int nt = 0; nt < 4; ++nt) {
                short8 bfr = ld_frag(&Ws[(wcol + nt * 16 + lm) * 34 + s * 16 + lq * 4]);
#pragma unroll
                for (int mt = 0; mt < 2; ++mt)
                    acc[mt][nt] = __builtin_amdgcn_mfma_f32_16x16x32_bf16(
                        afr[mt], bfr, acc[mt][nt], 0, 0, 0);
            }
        }
    }

    __syncthreads();
    unsigned short* hbuf = (unsigned short*)smem;  // [64][132]
#pragma unroll
    for (int mt = 0; mt < 2; ++mt)
#pragma unroll
        for (int nt = 0; nt < 4; ++nt)
#pragma unroll
            for (int r = 0; r < 4; ++r) {
                int row = wrow + mt * 16 + lq * 4 + r;
                int col = wcol + nt * 16 + lm;
                float v = acc[mt][nt][r] + bc1[a * H_N + col];
                v = v > 0.f ? v : 0.01f * v;
                hbuf[row * 132 + col] = f2bf(v);
            }
    __syncthreads();
    if (t < 64) {
        size_t arow = (size_t)a * B_N + b0g + b0 + t;
        const float* ap = &actions[arow * ACT_N];
        float bestv = ap[0];
        int bi = 0;
        for (int o = 1; o < ACT_N; ++o) {
            float v = ap[o];
            if (v > bestv) { bestv = v; bi = o; }
        }
        float q = bc2[a * ACT_N + bi];
        const float4* w4p = (const float4*)&wt_c2[((size_t)a * ACT_N + bi) * H_N];
        const uint2* hp2 = (const uint2*)&hbuf[t * 132];
#pragma unroll
        for (int h4 = 0; h4 < 32; ++h4) {
            float4 w4 = w4p[h4];
            uint2 hh = hp2[h4];
            q = fmaf(bflo(hh.x), w4.x, q);
            q = fmaf(bfhi(hh.x), w4.y, q);
            q = fmaf(bflo(hh.y), w4.z, q);
            q = fmaf(bfhi(hh.y), w4.w, q);
        }
        qout[arow] = q;
    }
}

extern "C" void kernel_launch(void* const* d_in, const int* in_sizes, int n_in,
                              void* d_out, int out_size, void* d_ws, size_t ws_size,
                              hipStream_t stream) {
    const float* obs     = (const float*)d_in[0];
    const float* actions = (const float*)d_in[1];
    const float* W_sa    = (const float*)d_in[2];
    const float* b_sa    = (const float*)d_in[3];
    const float* W_s     = (const float*)d_in[4];
    const float* b_s     = (const float*)d_in[5];
    const float* Wk      = (const float*)d_in[6];
    const float* Wsel    = (const float*)d_in[7];
    const float* Wv      = (const float*)d_in[8];
    const float* bv      = (const float*)d_in[9];
    const float* Wc1     = (const float*)d_in[10];
    const float* bc1     = (const float*)d_in[11];
    const float* Wc2     = (const float*)d_in[12];
    const float* bc2     = (const float*)d_in[13];
    float* out = (float*)d_out;
    char* ws = (char*)d_ws;

    size_t o = 0;
    float* gsumP = (float*)(ws + o); o += (size_t)36864 * 4;
    float* gsqP  = (float*)(ws + o); o += (size_t)36864 * 4;
    float* meanA = (float*)(ws + o); o += 2304 * 4;
    float* rstdA = (float*)(ws + o); o += 2304 * 4;
    unsigned* wt_l1 = (unsigned*)(ws + o); o += (size_t)393216 * 4;
    unsigned* wt_p1 = (unsigned*)(ws + o); o += (size_t)16384 * 4;
    unsigned* wt_p2 = (unsigned*)(ws + o); o += (size_t)8192 * 4;
    unsigned* wt_cr = (unsigned*)(ws + o); o += (size_t)262144 * 4;
    float* fb = (float*)(ws + o); o += (size_t)4096 * 4;
    float* wt_c2 = (float*)(ws + o); o += (size_t)32768 * 4;
    size_t fixed = o;

    int Bc = B_N;
    while (Bc > 128 && fixed + 12288ull * Bc > ws_size) Bc >>= 1;

    unsigned short* sa_us = (unsigned short*)(ws + o); o += (size_t)A_N * Bc * 128 * 2;
    unsigned short* se_us = (unsigned short*)(ws + o); o += (size_t)A_N * Bc * 128 * 2;
    unsigned short* ot_us = (unsigned short*)(ws + o); o += (size_t)A_N * Bc * 128 * 2;

    k_stats<<<dim3(A_N * 16), 256, 0, stream>>>(obs, actions, gsumP, gsqP);
    k_finalize<<<dim3(9), 256, 0, stream>>>(gsumP, gsqP, meanA, rstdA);
    k_wprep<<<dim3(BFE / 256), 256, 0, stream>>>(W_sa, W_s, Wk, Wsel, Wv, Wc1, Wc2,
                                                 meanA, rstdA, b_sa, b_s,
                                                 wt_l1, wt_p1, wt_p2, wt_cr, wt_c2, fb);

    for (int b0g = 0; b0g < B_N; b0g += Bc) {
        k_l1<<<dim3(Bc / 128, A_N), 512, 0, stream>>>(
            obs, actions, wt_l1, fb, sa_us, se_us, b0g, Bc);
        k_fused<<<dim3(Bc / 4), 256, 0, stream>>>(
            (const unsigned*)sa_us, (const unsigned*)se_us, wt_p1, wt_p2, bv,
            ot_us, Bc);
        k_critic<<<dim3(Bc / 64, A_N), 256, 0, stream>>>(
            (const unsigned*)se_us, (const unsigned*)ot_us, wt_cr, bc1,
            actions, wt_c2, bc2, out, b0g, Bc);
    }
}